// Round 3
// baseline (228.852 us; speedup 1.0000x reference)
//
#include <hip/hip_runtime.h>

#define DIMSZ 1024
#define NB 8
#define TSEQ 2048
#define MTOT (NB*TSEQ)   // 16384
#define CCH 64           // chunks per sequence
#define LCH (TSEQ/CCH)   // 32 steps per chunk
#define NCHAN (NB*DIMSZ) // 8192 independent channels

typedef __attribute__((ext_vector_type(8))) short short8v;
typedef __attribute__((ext_vector_type(4))) float f32x4;

__device__ __forceinline__ unsigned short f2bf(float f) {
  unsigned int u; __builtin_memcpy(&u, &f, 4);
  unsigned int r = u + 0x7FFF + ((u >> 16) & 1);   // RNE
  return (unsigned short)(r >> 16);
}
__device__ __forceinline__ float bf2f(unsigned short us) {
  unsigned int v = ((unsigned int)us) << 16;
  float f; __builtin_memcpy(&f, &v, 4); return f;
}

// async global->LDS, 16B per lane; LDS dest is wave-uniform base + lane*16
__device__ __forceinline__ void gload16(const void* g, void* l) {
  __builtin_amdgcn_global_load_lds(
      (const __attribute__((address_space(1))) void*)g,
      (__attribute__((address_space(3))) void*)l, 16, 0, 0);
}

// ---------------- cast x (f32) -> bf16, 4 elems/thread ----------------
__global__ __launch_bounds__(256) void cast_x_kernel(
    const float* __restrict__ in, unsigned short* __restrict__ out) {
  int i = blockIdx.x * 256 + threadIdx.x;
  float4 f = reinterpret_cast<const float4*>(in)[i];
  uint2 o;
  o.x = (unsigned)f2bf(f.x) | ((unsigned)f2bf(f.y) << 16);
  o.y = (unsigned)f2bf(f.z) | ((unsigned)f2bf(f.w) << 16);
  reinterpret_cast<uint2*>(out)[i] = o;
}

// ---------------- transpose + cast W [K][N] f32 -> WT [N][K] bf16 ----------------
__global__ __launch_bounds__(256) void transpose_cast_kernel(
    const float* __restrict__ W, unsigned short* __restrict__ WT) {
  __shared__ float tile[32][33];
  int tx = threadIdx.x & 31, ty = threadIdx.x >> 5;   // 32 x 8
  int row0 = blockIdx.y * 32, col0 = blockIdx.x * 32;
  #pragma unroll
  for (int j = 0; j < 32; j += 8)
    tile[ty + j][tx] = W[(size_t)(row0 + ty + j) * DIMSZ + col0 + tx];
  __syncthreads();
  #pragma unroll
  for (int j = 0; j < 32; j += 8)
    WT[(size_t)(col0 + ty + j) * DIMSZ + row0 + tx] = f2bf(tile[tx][ty + j]);
}

// ---------------- bf16 MFMA GEMM (m97 structure): C = A * BT^T + bias ----------------
// 128x128 tile, BK=64, 4 waves 2x2, global_load_lds width=16, LINEAR LDS [128][64].
#define BM 128
#define BN 128
#define BKK 64

template<int OUTBF>
__global__ __launch_bounds__(256) void gemm_bt_kernel(
    const unsigned short* __restrict__ A,
    const unsigned short* __restrict__ BT,
    void* __restrict__ Cv,
    const float* __restrict__ bias0,
    const float* __restrict__ bias1,
    int M, int N, int K, int Nsplit) {
  __shared__ __align__(16) unsigned short As[BM][BKK];  // linear, no pad (gload_lds dest)
  __shared__ __align__(16) unsigned short Bs[BN][BKK];
  const int tid  = threadIdx.x;
  const int brow = blockIdx.x * BM;
  const int bcol = blockIdx.y * BN;
  const int wid  = tid >> 6;
  const int lane = tid & 63;
  const int wr = wid >> 1, wc = wid & 1;
  const int lrow = lane & 15;
  const int lko  = (lane >> 4) * 8;
  const int grow = lane >> 3;        // staging: lane's row within 8-row group
  const int gcol = (lane & 7) * 8;   // staging: lane's col (elems)

  f32x4 acc[4][4];
  #pragma unroll
  for (int m = 0; m < 4; ++m)
    #pragma unroll
    for (int n = 0; n < 4; ++n)
      acc[m][n] = (f32x4){0.f, 0.f, 0.f, 0.f};

  for (int k0 = 0; k0 < K; k0 += BKK) {
    // stage: each wave issues 4+4 global_load_lds_dwordx4, 8 rows per instr.
    // LDS dest wave-uniform; lane i lands at base + i*16B = row i/8, colbyte (i&7)*16.
    #pragma unroll
    for (int j = 0; j < 4; ++j) {
      int r = wid * 32 + j * 8;
      gload16(&A [(size_t)(brow + r + grow) * K + k0 + gcol], &As[r][0]);
      gload16(&BT[(size_t)(bcol + r + grow) * K + k0 + gcol], &Bs[r][0]);
    }
    __syncthreads();   // drains vmcnt (m97 structure)
    #pragma unroll
    for (int kk = 0; kk < BKK; kk += 32) {
      short8v af[4], bf[4];
      #pragma unroll
      for (int m = 0; m < 4; ++m)
        af[m] = *reinterpret_cast<const short8v*>(&As[wr * 64 + m * 16 + lrow][kk + lko]);
      #pragma unroll
      for (int n = 0; n < 4; ++n)
        bf[n] = *reinterpret_cast<const short8v*>(&Bs[wc * 64 + n * 16 + lrow][kk + lko]);
      #pragma unroll
      for (int m = 0; m < 4; ++m)
        #pragma unroll
        for (int n = 0; n < 4; ++n)
          acc[m][n] = __builtin_amdgcn_mfma_f32_16x16x32_bf16(af[m], bf[n], acc[m][n], 0, 0, 0);
    }
    __syncthreads();
  }

  const int orow = brow + wr * 64;
  const int ocol = bcol + wc * 64;
  #pragma unroll
  for (int n = 0; n < 4; ++n) {
    int col = ocol + n * 16 + lrow;
    float b = (col < Nsplit) ? bias0[col] : bias1[col - Nsplit];
    #pragma unroll
    for (int m = 0; m < 4; ++m) {
      #pragma unroll
      for (int r = 0; r < 4; ++r) {
        int row = orow + m * 16 + (lane >> 4) * 4 + r;
        float val = acc[m][n][r] + b;
        if (OUTBF) {
          ((unsigned short*)Cv)[(size_t)row * N + col] = f2bf(val);
        } else {
          ((float*)Cv)[(size_t)row * N + col] = val;
        }
      }
    }
  }
}

// =================== WKV chunked parallel scan ===================
// State (p,a,b): A = a*e^p, B = b*e^p. Empty state (p=-1e30,a=b=0) reproduces
// the reference init and O[0]=v[0] through the uniform step rule.

__device__ __forceinline__ void wkv_step(float& p, float& a, float& b,
                                         float kt, float vt, float w) {
  float ww2 = p - w;
  float qq2 = fmaxf(ww2, kt);
  float e1 = __expf(ww2 - qq2);
  float e2 = __expf(kt - qq2);
  a = e1 * a + e2 * vt;
  b = e1 * b + e2;
  p = qq2;
}

// Pass 1: per-(chunk, channel-pair) local state from empty. 2 channels/thread.
__global__ __launch_bounds__(256) void wkv_chunk_state_kernel(
    const unsigned short* __restrict__ kv,
    const float* __restrict__ wdec,
    float* __restrict__ stP, float* __restrict__ stA, float* __restrict__ stB) {
  int idx = blockIdx.x * 256 + threadIdx.x;     // 0 .. CCH*NB*512-1
  int cp = idx & 511;
  int n = (idx >> 9) & (NB - 1);
  int chunk = idx >> 12;
  int c = cp * 2;
  float2 w2 = *reinterpret_cast<const float2*>(&wdec[c]);
  const unsigned short* base = kv + (size_t)(n * TSEQ + chunk * LCH) * 2048 + c;
  float p0 = -1e30f, a0 = 0.f, b0 = 0.f;
  float p1 = -1e30f, a1 = 0.f, b1 = 0.f;
  #pragma unroll 8
  for (int j = 0; j < LCH; ++j) {
    unsigned int kk = *reinterpret_cast<const unsigned int*>(&base[(size_t)j * 2048]);
    unsigned int vv = *reinterpret_cast<const unsigned int*>(&base[(size_t)j * 2048 + 1024]);
    wkv_step(p0, a0, b0, bf2f(kk & 0xffff), bf2f(vv & 0xffff), w2.x);
    wkv_step(p1, a1, b1, bf2f(kk >> 16),    bf2f(vv >> 16),    w2.y);
  }
  int soff = chunk * NCHAN + n * 1024 + c;
  *reinterpret_cast<float2*>(&stP[soff]) = make_float2(p0, p1);
  *reinterpret_cast<float2*>(&stA[soff]) = make_float2(a0, a1);
  *reinterpret_cast<float2*>(&stB[soff]) = make_float2(b0, b1);
}

// Pass 2: serial scan over chunk states per channel -> incoming prefixes.
__global__ __launch_bounds__(256) void wkv_scan_kernel(
    const float* __restrict__ wdec,
    float* __restrict__ stP, float* __restrict__ stA, float* __restrict__ stB) {
  int idx = blockIdx.x * 256 + threadIdx.x;   // [n][c]
  int c = idx & 1023;
  float decay = (float)LCH * wdec[c];
  float p = -1e30f, a = 0.f, b = 0.f;
  for (int i = 0; i < CCH; ++i) {
    int off = i * NCHAN + idx;
    float pc = stP[off], ac = stA[off], bc = stB[off];
    stP[off] = p; stA[off] = a; stB[off] = b;   // incoming prefix
    float pd = p - decay;
    float q = fmaxf(pd, pc);
    float e1 = __expf(pd - q);
    float e2 = __expf(pc - q);
    a = e1 * a + e2 * ac;
    b = e1 * b + e2 * bc;
    p = q;
  }
}

// Pass 3: replay each chunk from its incoming prefix, emitting outputs. 2 ch/thread.
__global__ __launch_bounds__(256) void wkv_out_kernel(
    const unsigned short* __restrict__ kv,
    const float* __restrict__ wdec, const float* __restrict__ ubon,
    const float* __restrict__ stP, const float* __restrict__ stA,
    const float* __restrict__ stB,
    unsigned short* __restrict__ O) {
  int idx = blockIdx.x * 256 + threadIdx.x;
  int cp = idx & 511;
  int n = (idx >> 9) & (NB - 1);
  int chunk = idx >> 12;
  int c = cp * 2;
  float2 w2 = *reinterpret_cast<const float2*>(&wdec[c]);
  float2 u2 = *reinterpret_cast<const float2*>(&ubon[c]);
  const unsigned short* base = kv + (size_t)(n * TSEQ + chunk * LCH) * 2048 + c;
  unsigned short* ob = O + (size_t)(n * TSEQ + chunk * LCH) * DIMSZ + c;
  int soff = chunk * NCHAN + n * 1024 + c;
  float2 pP = *reinterpret_cast<const float2*>(&stP[soff]);
  float2 pA = *reinterpret_cast<const float2*>(&stA[soff]);
  float2 pB = *reinterpret_cast<const float2*>(&stB[soff]);
  float p0 = pP.x, a0 = pA.x, b0 = pB.x;
  float p1 = pP.y, a1 = pA.y, b1 = pB.y;
  #pragma unroll 4
  for (int j = 0; j < LCH; ++j) {
    unsigned int kk = *reinterpret_cast<const unsigned int*>(&base[(size_t)j * 2048]);
    unsigned int vv = *reinterpret_cast<const unsigned int*>(&base[(size_t)j * 2048 + 1024]);
    float k0 = bf2f(kk & 0xffff), k1 = bf2f(kk >> 16);
    float v0 = bf2f(vv & 0xffff), v1 = bf2f(vv >> 16);
    // outputs from incoming state (bonus u)
    float ww0 = u2.x + k0, ww1 = u2.y + k1;
    float qq0 = fmaxf(ww0, p0), qq1 = fmaxf(ww1, p1);
    float e10 = __expf(p0 - qq0), e20 = __expf(ww0 - qq0);
    float e11 = __expf(p1 - qq1), e21 = __expf(ww1 - qq1);
    float o0 = (e10 * a0 + e20 * v0) * __builtin_amdgcn_rcpf(e10 * b0 + e20);
    float o1 = (e11 * a1 + e21 * v1) * __builtin_amdgcn_rcpf(e11 * b1 + e21);
    *reinterpret_cast<unsigned int*>(&ob[(size_t)j * DIMSZ]) =
        (unsigned)f2bf(o0) | ((unsigned)f2bf(o1) << 16);
    // state update (decay w)
    wkv_step(p0, a0, b0, k0, v0, w2.x);
    wkv_step(p1, a1, b1, k1, v1, w2.y);
  }
}

extern "C" void kernel_launch(void* const* d_in, const int* in_sizes, int n_in,
                              void* d_out, int out_size, void* d_ws, size_t ws_size,
                              hipStream_t stream) {
  const float* x  = (const float*)d_in[0];
  // d_in[1]=Wq, d_in[2]=bq: unused by the reference forward
  const float* Wk = (const float*)d_in[3];
  const float* bk = (const float*)d_in[4];
  const float* Wv = (const float*)d_in[5];
  const float* bv = (const float*)d_in[6];
  const float* wr = (const float*)d_in[7];
  const float* ur = (const float*)d_in[8];
  const float* Wo = (const float*)d_in[9];
  const float* bo = (const float*)d_in[10];
  float* out = (float*)d_out;

  char* ws = (char*)d_ws;
  unsigned short* xb   = (unsigned short*)(ws);               // 32MB  [16384][1024] bf16 (reused as O)
  unsigned short* WTkv = (unsigned short*)(ws + 33554432);    // 4MB   [2048][1024] bf16 (Wk^T ; Wv^T)
  unsigned short* WoT  = (unsigned short*)(ws + 37748736);    // 2MB   [1024][1024] bf16
  unsigned short* kvb  = (unsigned short*)(ws + 39845888);    // 64MB  [16384][2048] bf16

  // chunk-state scratch lives in d_out (64MB f32): fully overwritten by the
  // final GEMM afterwards, so this is free scratch during the wkv phase.
  float* stP = out;                       // 2MB (CCH*NCHAN floats)
  float* stA = out + CCH * NCHAN;         // 2MB
  float* stB = out + 2 * CCH * NCHAN;     // 2MB

  cast_x_kernel<<<dim3(16384), dim3(256), 0, stream>>>(x, xb);
  transpose_cast_kernel<<<dim3(32, 32), dim3(256), 0, stream>>>(Wk, WTkv);
  transpose_cast_kernel<<<dim3(32, 32), dim3(256), 0, stream>>>(Wv, WTkv + 1024 * 1024);
  transpose_cast_kernel<<<dim3(32, 32), dim3(256), 0, stream>>>(Wo, WoT);

  // k|v projection: [16384][1024] @ [1024][2048] -> bf16 kv buffer (+bk|bv)
  gemm_bt_kernel<1><<<dim3(128, 16), dim3(256), 0, stream>>>(
      xb, WTkv, (void*)kvb, bk, bv, MTOT, 2048, 1024, 1024);

  // WKV chunked scan -> O (bf16) into xb (its x-bf16 contents are consumed)
  wkv_chunk_state_kernel<<<dim3(CCH * NB * 512 / 256), dim3(256), 0, stream>>>(
      kvb, wr, stP, stA, stB);
  wkv_scan_kernel<<<dim3(NCHAN / 256), dim3(256), 0, stream>>>(wr, stP, stA, stB);
  wkv_out_kernel<<<dim3(CCH * NB * 512 / 256), dim3(256), 0, stream>>>(
      kvb, wr, ur, stP, stA, stB, xb);

  // output projection: [16384][1024] @ [1024][1024] -> f32 d_out (+bo)
  gemm_bt_kernel<0><<<dim3(128, 8), dim3(256), 0, stream>>>(
      xb, WoT, (void*)out, bo, bo, MTOT, 1024, 1024, 1024);
}

// Round 4
// 224.904 us; speedup vs baseline: 1.0176x; 1.0176x over previous
//
#include <hip/hip_runtime.h>

#define DIMSZ 1024
#define NB 8
#define TSEQ 2048
#define MTOT (NB*TSEQ)   // 16384
#define CCH 64           // chunks per sequence
#define LCH (TSEQ/CCH)   // 32 steps per chunk
#define NCHAN (NB*DIMSZ) // 8192 independent channels

typedef __attribute__((ext_vector_type(8))) short short8v;
typedef __attribute__((ext_vector_type(4))) float f32x4;

__device__ __forceinline__ unsigned short f2bf(float f) {
  unsigned int u; __builtin_memcpy(&u, &f, 4);
  unsigned int r = u + 0x7FFF + ((u >> 16) & 1);   // RNE
  return (unsigned short)(r >> 16);
}
__device__ __forceinline__ float bf2f(unsigned short us) {
  unsigned int v = ((unsigned int)us) << 16;
  float f; __builtin_memcpy(&f, &v, 4); return f;
}

// async global->LDS, 16B per lane; LDS dest is wave-uniform base + lane*16
__device__ __forceinline__ void gload16(const void* g, void* l) {
  __builtin_amdgcn_global_load_lds(
      (const __attribute__((address_space(1))) void*)g,
      (__attribute__((address_space(3))) void*)l, 16, 0, 0);
}

// ---------------- cast x (f32) -> bf16, 4 elems/thread ----------------
__global__ __launch_bounds__(256) void cast_x_kernel(
    const float* __restrict__ in, unsigned short* __restrict__ out) {
  int i = blockIdx.x * 256 + threadIdx.x;
  float4 f = reinterpret_cast<const float4*>(in)[i];
  uint2 o;
  o.x = (unsigned)f2bf(f.x) | ((unsigned)f2bf(f.y) << 16);
  o.y = (unsigned)f2bf(f.z) | ((unsigned)f2bf(f.w) << 16);
  reinterpret_cast<uint2*>(out)[i] = o;
}

// ---------------- transpose + cast W [K][N] f32 -> WT [N][K] bf16 ----------------
__global__ __launch_bounds__(256) void transpose_cast_kernel(
    const float* __restrict__ W, unsigned short* __restrict__ WT) {
  __shared__ float tile[32][33];
  int tx = threadIdx.x & 31, ty = threadIdx.x >> 5;   // 32 x 8
  int row0 = blockIdx.y * 32, col0 = blockIdx.x * 32;
  #pragma unroll
  for (int j = 0; j < 32; j += 8)
    tile[ty + j][tx] = W[(size_t)(row0 + ty + j) * DIMSZ + col0 + tx];
  __syncthreads();
  #pragma unroll
  for (int j = 0; j < 32; j += 8)
    WT[(size_t)(col0 + ty + j) * DIMSZ + row0 + tx] = f2bf(tile[tx][ty + j]);
}

// ---------------- bf16 MFMA GEMM: C = A * BT^T + bias ----------------
// 128x128 tile, BK=64, 4 waves 2x2. global_load_lds width=16 with
// BOTH-SIDES XOR swizzle (rule #21): LDS dest linear; the global SOURCE is
// pre-swizzled so effective layout is byte(row,cb)=row*128+(cb^((row&7)<<4));
// reads apply the same XOR -> 2-way max bank alias (free).
#define BM 128
#define BN 128
#define BKK 64

template<int OUTBF>
__global__ __launch_bounds__(256) void gemm_bt_kernel(
    const unsigned short* __restrict__ A,
    const unsigned short* __restrict__ BT,
    void* __restrict__ Cv,
    const float* __restrict__ bias0,
    const float* __restrict__ bias1,
    int M, int N, int K, int Nsplit) {
  __shared__ __align__(16) unsigned short As[BM][BKK];  // linear dest (gload_lds)
  __shared__ __align__(16) unsigned short Bs[BN][BKK];
  const int tid  = threadIdx.x;

  // XCD-chunked bijective block swizzle (nwg % 8 == 0 for all our launches)
  const int gx   = M >> 7;                 // blocks along M
  const int nwg  = gridDim.x;
  const int bid  = blockIdx.x;
  const int swz  = (bid & 7) * (nwg >> 3) + (bid >> 3);
  const int brow = (swz % gx) * BM;
  const int bcol = (swz / gx) * BN;

  const int wid  = tid >> 6;
  const int lane = tid & 63;
  const int wr = wid >> 1, wc = wid & 1;
  const int lrow = lane & 15;
  const int lko  = (lane >> 4) * 8;
  const int grow = lane >> 3;                      // staging row within 8-row group
  const int gcol = ((lane & 7) ^ grow) * 8;        // pre-swizzled source col (elems)
  const int rdsw = (lrow & 7) << 4;                // read-side XOR (bytes)

  f32x4 acc[4][4];
  #pragma unroll
  for (int m = 0; m < 4; ++m)
    #pragma unroll
    for (int n = 0; n < 4; ++n)
      acc[m][n] = (f32x4){0.f, 0.f, 0.f, 0.f};

  for (int k0 = 0; k0 < K; k0 += BKK) {
    #pragma unroll
    for (int j = 0; j < 4; ++j) {
      int r = wid * 32 + j * 8;
      gload16(&A [(size_t)(brow + r + grow) * K + k0 + gcol], &As[r][0]);
      gload16(&BT[(size_t)(bcol + r + grow) * K + k0 + gcol], &Bs[r][0]);
    }
    __syncthreads();
    #pragma unroll
    for (int kk = 0; kk < BKK; kk += 32) {
      short8v af[4], bf[4];
      #pragma unroll
      for (int m = 0; m < 4; ++m) {
        int row = wr * 64 + m * 16 + lrow;
        af[m] = *reinterpret_cast<const short8v*>(
            (const char*)As + row * (BKK * 2) + (((kk + lko) * 2) ^ rdsw));
      }
      #pragma unroll
      for (int n = 0; n < 4; ++n) {
        int row = wc * 64 + n * 16 + lrow;
        bf[n] = *reinterpret_cast<const short8v*>(
            (const char*)Bs + row * (BKK * 2) + (((kk + lko) * 2) ^ rdsw));
      }
      #pragma unroll
      for (int m = 0; m < 4; ++m)
        #pragma unroll
        for (int n = 0; n < 4; ++n)
          acc[m][n] = __builtin_amdgcn_mfma_f32_16x16x32_bf16(af[m], bf[n], acc[m][n], 0, 0, 0);
    }
    __syncthreads();
  }

  const int orow = brow + wr * 64;
  const int ocol = bcol + wc * 64;
  #pragma unroll
  for (int n = 0; n < 4; ++n) {
    int col = ocol + n * 16 + lrow;
    float b = (col < Nsplit) ? bias0[col] : bias1[col - Nsplit];
    #pragma unroll
    for (int m = 0; m < 4; ++m) {
      #pragma unroll
      for (int r = 0; r < 4; ++r) {
        int row = orow + m * 16 + (lane >> 4) * 4 + r;
        float val = acc[m][n][r] + b;
        if (OUTBF) {
          ((unsigned short*)Cv)[(size_t)row * N + col] = f2bf(val);
        } else {
          ((float*)Cv)[(size_t)row * N + col] = val;
        }
      }
    }
  }
}

// =================== WKV chunked parallel scan ===================
// State (p,a,b): A = a*e^p, B = b*e^p. Empty state (p=-1e30,a=b=0) reproduces
// the reference init and O[0]=v[0] through the uniform step rule.

__device__ __forceinline__ void wkv_step(float& p, float& a, float& b,
                                         float kt, float vt, float w) {
  float ww2 = p - w;
  float qq2 = fmaxf(ww2, kt);
  float e1 = __expf(ww2 - qq2);
  float e2 = __expf(kt - qq2);
  a = e1 * a + e2 * vt;
  b = e1 * b + e2;
  p = qq2;
}

// Pass 1: per-(chunk, channel-pair) local state from empty. 2 channels/thread.
__global__ __launch_bounds__(256) void wkv_chunk_state_kernel(
    const unsigned short* __restrict__ kv,
    const float* __restrict__ wdec,
    float* __restrict__ stP, float* __restrict__ stA, float* __restrict__ stB) {
  int idx = blockIdx.x * 256 + threadIdx.x;     // 0 .. CCH*NB*512-1
  int cp = idx & 511;
  int n = (idx >> 9) & (NB - 1);
  int chunk = idx >> 12;
  int c = cp * 2;
  float2 w2 = *reinterpret_cast<const float2*>(&wdec[c]);
  const unsigned short* base = kv + (size_t)(n * TSEQ + chunk * LCH) * 2048 + c;
  float p0 = -1e30f, a0 = 0.f, b0 = 0.f;
  float p1 = -1e30f, a1 = 0.f, b1 = 0.f;
  #pragma unroll 8
  for (int j = 0; j < LCH; ++j) {
    unsigned int kk = *reinterpret_cast<const unsigned int*>(&base[(size_t)j * 2048]);
    unsigned int vv = *reinterpret_cast<const unsigned int*>(&base[(size_t)j * 2048 + 1024]);
    wkv_step(p0, a0, b0, bf2f(kk & 0xffff), bf2f(vv & 0xffff), w2.x);
    wkv_step(p1, a1, b1, bf2f(kk >> 16),    bf2f(vv >> 16),    w2.y);
  }
  int soff = chunk * NCHAN + n * 1024 + c;
  *reinterpret_cast<float2*>(&stP[soff]) = make_float2(p0, p1);
  *reinterpret_cast<float2*>(&stA[soff]) = make_float2(a0, a1);
  *reinterpret_cast<float2*>(&stB[soff]) = make_float2(b0, b1);
}

// Pass 2: serial scan over chunk states per channel -> incoming prefixes.
__global__ __launch_bounds__(256) void wkv_scan_kernel(
    const float* __restrict__ wdec,
    float* __restrict__ stP, float* __restrict__ stA, float* __restrict__ stB) {
  int idx = blockIdx.x * 256 + threadIdx.x;   // [n][c]
  int c = idx & 1023;
  float decay = (float)LCH * wdec[c];
  float p = -1e30f, a = 0.f, b = 0.f;
  for (int i = 0; i < CCH; ++i) {
    int off = i * NCHAN + idx;
    float pc = stP[off], ac = stA[off], bc = stB[off];
    stP[off] = p; stA[off] = a; stB[off] = b;   // incoming prefix
    float pd = p - decay;
    float q = fmaxf(pd, pc);
    float e1 = __expf(pd - q);
    float e2 = __expf(pc - q);
    a = e1 * a + e2 * ac;
    b = e1 * b + e2 * bc;
    p = q;
  }
}

// Pass 3: replay each chunk from its incoming prefix, emitting outputs. 2 ch/thread.
__global__ __launch_bounds__(256) void wkv_out_kernel(
    const unsigned short* __restrict__ kv,
    const float* __restrict__ wdec, const float* __restrict__ ubon,
    const float* __restrict__ stP, const float* __restrict__ stA,
    const float* __restrict__ stB,
    unsigned short* __restrict__ O) {
  int idx = blockIdx.x * 256 + threadIdx.x;
  int cp = idx & 511;
  int n = (idx >> 9) & (NB - 1);
  int chunk = idx >> 12;
  int c = cp * 2;
  float2 w2 = *reinterpret_cast<const float2*>(&wdec[c]);
  float2 u2 = *reinterpret_cast<const float2*>(&ubon[c]);
  const unsigned short* base = kv + (size_t)(n * TSEQ + chunk * LCH) * 2048 + c;
  unsigned short* ob = O + (size_t)(n * TSEQ + chunk * LCH) * DIMSZ + c;
  int soff = chunk * NCHAN + n * 1024 + c;
  float2 pP = *reinterpret_cast<const float2*>(&stP[soff]);
  float2 pA = *reinterpret_cast<const float2*>(&stA[soff]);
  float2 pB = *reinterpret_cast<const float2*>(&stB[soff]);
  float p0 = pP.x, a0 = pA.x, b0 = pB.x;
  float p1 = pP.y, a1 = pA.y, b1 = pB.y;
  #pragma unroll 4
  for (int j = 0; j < LCH; ++j) {
    unsigned int kk = *reinterpret_cast<const unsigned int*>(&base[(size_t)j * 2048]);
    unsigned int vv = *reinterpret_cast<const unsigned int*>(&base[(size_t)j * 2048 + 1024]);
    float k0 = bf2f(kk & 0xffff), k1 = bf2f(kk >> 16);
    float v0 = bf2f(vv & 0xffff), v1 = bf2f(vv >> 16);
    // outputs from incoming state (bonus u)
    float ww0 = u2.x + k0, ww1 = u2.y + k1;
    float qq0 = fmaxf(ww0, p0), qq1 = fmaxf(ww1, p1);
    float e10 = __expf(p0 - qq0), e20 = __expf(ww0 - qq0);
    float e11 = __expf(p1 - qq1), e21 = __expf(ww1 - qq1);
    float o0 = (e10 * a0 + e20 * v0) * __builtin_amdgcn_rcpf(e10 * b0 + e20);
    float o1 = (e11 * a1 + e21 * v1) * __builtin_amdgcn_rcpf(e11 * b1 + e21);
    *reinterpret_cast<unsigned int*>(&ob[(size_t)j * DIMSZ]) =
        (unsigned)f2bf(o0) | ((unsigned)f2bf(o1) << 16);
    // state update (decay w)
    wkv_step(p0, a0, b0, k0, v0, w2.x);
    wkv_step(p1, a1, b1, k1, v1, w2.y);
  }
}

extern "C" void kernel_launch(void* const* d_in, const int* in_sizes, int n_in,
                              void* d_out, int out_size, void* d_ws, size_t ws_size,
                              hipStream_t stream) {
  const float* x  = (const float*)d_in[0];
  // d_in[1]=Wq, d_in[2]=bq: unused by the reference forward
  const float* Wk = (const float*)d_in[3];
  const float* bk = (const float*)d_in[4];
  const float* Wv = (const float*)d_in[5];
  const float* bv = (const float*)d_in[6];
  const float* wr = (const float*)d_in[7];
  const float* ur = (const float*)d_in[8];
  const float* Wo = (const float*)d_in[9];
  const float* bo = (const float*)d_in[10];
  float* out = (float*)d_out;

  char* ws = (char*)d_ws;
  unsigned short* xb   = (unsigned short*)(ws);               // 32MB  [16384][1024] bf16 (reused as O)
  unsigned short* WTkv = (unsigned short*)(ws + 33554432);    // 4MB   [2048][1024] bf16 (Wk^T ; Wv^T)
  unsigned short* WoT  = (unsigned short*)(ws + 37748736);    // 2MB   [1024][1024] bf16
  unsigned short* kvb  = (unsigned short*)(ws + 39845888);    // 64MB  [16384][2048] bf16

  // chunk-state scratch lives in d_out (64MB f32): fully overwritten by the
  // final GEMM afterwards, so this is free scratch during the wkv phase.
  float* stP = out;                       // 2MB (CCH*NCHAN floats)
  float* stA = out + CCH * NCHAN;         // 2MB
  float* stB = out + 2 * CCH * NCHAN;     // 2MB

  cast_x_kernel<<<dim3(16384), dim3(256), 0, stream>>>(x, xb);
  transpose_cast_kernel<<<dim3(32, 32), dim3(256), 0, stream>>>(Wk, WTkv);
  transpose_cast_kernel<<<dim3(32, 32), dim3(256), 0, stream>>>(Wv, WTkv + 1024 * 1024);
  transpose_cast_kernel<<<dim3(32, 32), dim3(256), 0, stream>>>(Wo, WoT);

  // k|v projection: [16384][1024] @ [1024][2048] -> bf16 kv buffer (+bk|bv)
  gemm_bt_kernel<1><<<dim3(128 * 16), dim3(256), 0, stream>>>(
      xb, WTkv, (void*)kvb, bk, bv, MTOT, 2048, 1024, 1024);

  // WKV chunked scan -> O (bf16) into xb (its x-bf16 contents are consumed)
  wkv_chunk_state_kernel<<<dim3(CCH * NB * 512 / 256), dim3(256), 0, stream>>>(
      kvb, wr, stP, stA, stB);
  wkv_scan_kernel<<<dim3(NCHAN / 256), dim3(256), 0, stream>>>(wr, stP, stA, stB);
  wkv_out_kernel<<<dim3(CCH * NB * 512 / 256), dim3(256), 0, stream>>>(
      kvb, wr, ur, stP, stA, stB, xb);

  // output projection: [16384][1024] @ [1024][1024] -> f32 d_out (+bo)
  gemm_bt_kernel<0><<<dim3(128 * 8), dim3(256), 0, stream>>>(
      xb, WoT, (void*)out, bo, bo, MTOT, 1024, 1024, 1024);
}

// Round 5
// 201.652 us; speedup vs baseline: 1.1349x; 1.1153x over previous
//
#include <hip/hip_runtime.h>

#define DIMSZ 1024
#define NB 8
#define TSEQ 2048
#define MTOT (NB*TSEQ)   // 16384
#define CCH 64           // chunks per sequence
#define LCH (TSEQ/CCH)   // 32 steps per chunk
#define NCHAN (NB*DIMSZ) // 8192 independent channels

typedef __attribute__((ext_vector_type(8))) short short8v;
typedef __attribute__((ext_vector_type(4))) float f32x4;

__device__ __forceinline__ unsigned short f2bf(float f) {
  unsigned int u; __builtin_memcpy(&u, &f, 4);
  unsigned int r = u + 0x7FFF + ((u >> 16) & 1);   // RNE
  return (unsigned short)(r >> 16);
}
__device__ __forceinline__ float bf2f(unsigned short us) {
  unsigned int v = ((unsigned int)us) << 16;
  float f; __builtin_memcpy(&f, &v, 4); return f;
}

// async global->LDS, 16B per lane; LDS dest is wave-uniform base + lane*16
__device__ __forceinline__ void gload16(const void* g, void* l) {
  __builtin_amdgcn_global_load_lds(
      (const __attribute__((address_space(1))) void*)g,
      (__attribute__((address_space(3))) void*)l, 16, 0, 0);
}

// ---------------- cast x (f32) -> bf16, 4 elems/thread ----------------
__global__ __launch_bounds__(256) void cast_x_kernel(
    const float* __restrict__ in, unsigned short* __restrict__ out) {
  int i = blockIdx.x * 256 + threadIdx.x;
  float4 f = reinterpret_cast<const float4*>(in)[i];
  uint2 o;
  o.x = (unsigned)f2bf(f.x) | ((unsigned)f2bf(f.y) << 16);
  o.y = (unsigned)f2bf(f.z) | ((unsigned)f2bf(f.w) << 16);
  reinterpret_cast<uint2*>(out)[i] = o;
}

// ---------------- transpose + cast W [K][N] f32 -> WT [N][K] bf16 ----------------
__global__ __launch_bounds__(256) void transpose_cast_kernel(
    const float* __restrict__ W, unsigned short* __restrict__ WT) {
  __shared__ float tile[32][33];
  int tx = threadIdx.x & 31, ty = threadIdx.x >> 5;   // 32 x 8
  int row0 = blockIdx.y * 32, col0 = blockIdx.x * 32;
  #pragma unroll
  for (int j = 0; j < 32; j += 8)
    tile[ty + j][tx] = W[(size_t)(row0 + ty + j) * DIMSZ + col0 + tx];
  __syncthreads();
  #pragma unroll
  for (int j = 0; j < 32; j += 8)
    WT[(size_t)(col0 + ty + j) * DIMSZ + row0 + tx] = f2bf(tile[tx][ty + j]);
}

// ---------------- bf16 MFMA GEMM: C = A * BT^T + bias ----------------
// 128x128 tile, BK=64, 4 waves 2x2. global_load_lds width=16 with BOTH-SIDES
// XOR swizzle (rule #21): linear LDS dest; global SOURCE pre-swizzled so the
// effective layout is byte(row,cb)=row*128+(cb^((row&7)<<4)); reads apply the
// same XOR -> bank-conflict-free (verified: SQ_LDS_BANK_CONFLICT 25.2M -> 0).
// Grid is 2-D, blockIdx.x fast along M: consecutive blocks share the B-tile
// and stream A (R4 showed remapping this costs 3x L2-miss traffic).
#define BM 128
#define BN 128
#define BKK 64

template<int OUTBF>
__global__ __launch_bounds__(256) void gemm_bt_kernel(
    const unsigned short* __restrict__ A,
    const unsigned short* __restrict__ BT,
    void* __restrict__ Cv,
    const float* __restrict__ bias0,
    const float* __restrict__ bias1,
    int M, int N, int K, int Nsplit) {
  __shared__ __align__(16) unsigned short As[BM][BKK];  // linear dest (gload_lds)
  __shared__ __align__(16) unsigned short Bs[BN][BKK];
  const int tid  = threadIdx.x;
  const int brow = blockIdx.x * BM;
  const int bcol = blockIdx.y * BN;

  const int wid  = tid >> 6;
  const int lane = tid & 63;
  const int wr = wid >> 1, wc = wid & 1;
  const int lrow = lane & 15;
  const int lko  = (lane >> 4) * 8;
  const int grow = lane >> 3;                      // staging row within 8-row group
  const int gcol = ((lane & 7) ^ grow) * 8;        // pre-swizzled source col (elems)
  const int rdsw = (lrow & 7) << 4;                // read-side XOR (bytes)

  f32x4 acc[4][4];
  #pragma unroll
  for (int m = 0; m < 4; ++m)
    #pragma unroll
    for (int n = 0; n < 4; ++n)
      acc[m][n] = (f32x4){0.f, 0.f, 0.f, 0.f};

  for (int k0 = 0; k0 < K; k0 += BKK) {
    #pragma unroll
    for (int j = 0; j < 4; ++j) {
      int r = wid * 32 + j * 8;
      gload16(&A [(size_t)(brow + r + grow) * K + k0 + gcol], &As[r][0]);
      gload16(&BT[(size_t)(bcol + r + grow) * K + k0 + gcol], &Bs[r][0]);
    }
    __syncthreads();
    #pragma unroll
    for (int kk = 0; kk < BKK; kk += 32) {
      short8v af[4], bf[4];
      #pragma unroll
      for (int m = 0; m < 4; ++m) {
        int row = wr * 64 + m * 16 + lrow;
        af[m] = *reinterpret_cast<const short8v*>(
            (const char*)As + row * (BKK * 2) + (((kk + lko) * 2) ^ rdsw));
      }
      #pragma unroll
      for (int n = 0; n < 4; ++n) {
        int row = wc * 64 + n * 16 + lrow;
        bf[n] = *reinterpret_cast<const short8v*>(
            (const char*)Bs + row * (BKK * 2) + (((kk + lko) * 2) ^ rdsw));
      }
      #pragma unroll
      for (int m = 0; m < 4; ++m)
        #pragma unroll
        for (int n = 0; n < 4; ++n)
          acc[m][n] = __builtin_amdgcn_mfma_f32_16x16x32_bf16(af[m], bf[n], acc[m][n], 0, 0, 0);
    }
    __syncthreads();
  }

  const int orow = brow + wr * 64;
  const int ocol = bcol + wc * 64;
  #pragma unroll
  for (int n = 0; n < 4; ++n) {
    int col = ocol + n * 16 + lrow;
    float b = (col < Nsplit) ? bias0[col] : bias1[col - Nsplit];
    #pragma unroll
    for (int m = 0; m < 4; ++m) {
      #pragma unroll
      for (int r = 0; r < 4; ++r) {
        int row = orow + m * 16 + (lane >> 4) * 4 + r;
        float val = acc[m][n][r] + b;
        if (OUTBF) {
          ((unsigned short*)Cv)[(size_t)row * N + col] = f2bf(val);
        } else {
          ((float*)Cv)[(size_t)row * N + col] = val;
        }
      }
    }
  }
}

// =================== WKV chunked parallel scan ===================
// State (p,a,b): A = a*e^p, B = b*e^p. Empty state (p=-1e30,a=b=0) reproduces
// the reference init and O[0]=v[0] through the uniform step rule.

__device__ __forceinline__ void wkv_step(float& p, float& a, float& b,
                                         float kt, float vt, float w) {
  float ww2 = p - w;
  float qq2 = fmaxf(ww2, kt);
  float e1 = __expf(ww2 - qq2);
  float e2 = __expf(kt - qq2);
  a = e1 * a + e2 * vt;
  b = e1 * b + e2;
  p = qq2;
}

// Pass 1: per-(chunk, channel-pair) local state from empty. 2 channels/thread.
__global__ __launch_bounds__(256) void wkv_chunk_state_kernel(
    const unsigned short* __restrict__ kv,
    const float* __restrict__ wdec,
    float* __restrict__ stP, float* __restrict__ stA, float* __restrict__ stB) {
  int idx = blockIdx.x * 256 + threadIdx.x;     // 0 .. CCH*NB*512-1
  int cp = idx & 511;
  int n = (idx >> 9) & (NB - 1);
  int chunk = idx >> 12;
  int c = cp * 2;
  float2 w2 = *reinterpret_cast<const float2*>(&wdec[c]);
  const unsigned short* base = kv + (size_t)(n * TSEQ + chunk * LCH) * 2048 + c;
  float p0 = -1e30f, a0 = 0.f, b0 = 0.f;
  float p1 = -1e30f, a1 = 0.f, b1 = 0.f;
  #pragma unroll 8
  for (int j = 0; j < LCH; ++j) {
    unsigned int kk = *reinterpret_cast<const unsigned int*>(&base[(size_t)j * 2048]);
    unsigned int vv = *reinterpret_cast<const unsigned int*>(&base[(size_t)j * 2048 + 1024]);
    wkv_step(p0, a0, b0, bf2f(kk & 0xffff), bf2f(vv & 0xffff), w2.x);
    wkv_step(p1, a1, b1, bf2f(kk >> 16),    bf2f(vv >> 16),    w2.y);
  }
  int soff = chunk * NCHAN + n * 1024 + c;
  *reinterpret_cast<float2*>(&stP[soff]) = make_float2(p0, p1);
  *reinterpret_cast<float2*>(&stA[soff]) = make_float2(a0, a1);
  *reinterpret_cast<float2*>(&stB[soff]) = make_float2(b0, b1);
}

// Pass 2: serial scan over chunk states per channel -> incoming prefixes.
__global__ __launch_bounds__(256) void wkv_scan_kernel(
    const float* __restrict__ wdec,
    float* __restrict__ stP, float* __restrict__ stA, float* __restrict__ stB) {
  int idx = blockIdx.x * 256 + threadIdx.x;   // [n][c]
  int c = idx & 1023;
  float decay = (float)LCH * wdec[c];
  float p = -1e30f, a = 0.f, b = 0.f;
  for (int i = 0; i < CCH; ++i) {
    int off = i * NCHAN + idx;
    float pc = stP[off], ac = stA[off], bc = stB[off];
    stP[off] = p; stA[off] = a; stB[off] = b;   // incoming prefix
    float pd = p - decay;
    float q = fmaxf(pd, pc);
    float e1 = __expf(pd - q);
    float e2 = __expf(pc - q);
    a = e1 * a + e2 * ac;
    b = e1 * b + e2 * bc;
    p = q;
  }
}

// Pass 3: replay each chunk from its incoming prefix, emitting outputs. 2 ch/thread.
__global__ __launch_bounds__(256) void wkv_out_kernel(
    const unsigned short* __restrict__ kv,
    const float* __restrict__ wdec, const float* __restrict__ ubon,
    const float* __restrict__ stP, const float* __restrict__ stA,
    const float* __restrict__ stB,
    unsigned short* __restrict__ O) {
  int idx = blockIdx.x * 256 + threadIdx.x;
  int cp = idx & 511;
  int n = (idx >> 9) & (NB - 1);
  int chunk = idx >> 12;
  int c = cp * 2;
  float2 w2 = *reinterpret_cast<const float2*>(&wdec[c]);
  float2 u2 = *reinterpret_cast<const float2*>(&ubon[c]);
  const unsigned short* base = kv + (size_t)(n * TSEQ + chunk * LCH) * 2048 + c;
  unsigned short* ob = O + (size_t)(n * TSEQ + chunk * LCH) * DIMSZ + c;
  int soff = chunk * NCHAN + n * 1024 + c;
  float2 pP = *reinterpret_cast<const float2*>(&stP[soff]);
  float2 pA = *reinterpret_cast<const float2*>(&stA[soff]);
  float2 pB = *reinterpret_cast<const float2*>(&stB[soff]);
  float p0 = pP.x, a0 = pA.x, b0 = pB.x;
  float p1 = pP.y, a1 = pA.y, b1 = pB.y;
  #pragma unroll 4
  for (int j = 0; j < LCH; ++j) {
    unsigned int kk = *reinterpret_cast<const unsigned int*>(&base[(size_t)j * 2048]);
    unsigned int vv = *reinterpret_cast<const unsigned int*>(&base[(size_t)j * 2048 + 1024]);
    float k0 = bf2f(kk & 0xffff), k1 = bf2f(kk >> 16);
    float v0 = bf2f(vv & 0xffff), v1 = bf2f(vv >> 16);
    // outputs from incoming state (bonus u)
    float ww0 = u2.x + k0, ww1 = u2.y + k1;
    float qq0 = fmaxf(ww0, p0), qq1 = fmaxf(ww1, p1);
    float e10 = __expf(p0 - qq0), e20 = __expf(ww0 - qq0);
    float e11 = __expf(p1 - qq1), e21 = __expf(ww1 - qq1);
    float o0 = (e10 * a0 + e20 * v0) * __builtin_amdgcn_rcpf(e10 * b0 + e20);
    float o1 = (e11 * a1 + e21 * v1) * __builtin_amdgcn_rcpf(e11 * b1 + e21);
    *reinterpret_cast<unsigned int*>(&ob[(size_t)j * DIMSZ]) =
        (unsigned)f2bf(o0) | ((unsigned)f2bf(o1) << 16);
    // state update (decay w)
    wkv_step(p0, a0, b0, k0, v0, w2.x);
    wkv_step(p1, a1, b1, k1, v1, w2.y);
  }
}

extern "C" void kernel_launch(void* const* d_in, const int* in_sizes, int n_in,
                              void* d_out, int out_size, void* d_ws, size_t ws_size,
                              hipStream_t stream) {
  const float* x  = (const float*)d_in[0];
  // d_in[1]=Wq, d_in[2]=bq: unused by the reference forward
  const float* Wk = (const float*)d_in[3];
  const float* bk = (const float*)d_in[4];
  const float* Wv = (const float*)d_in[5];
  const float* bv = (const float*)d_in[6];
  const float* wr = (const float*)d_in[7];
  const float* ur = (const float*)d_in[8];
  const float* Wo = (const float*)d_in[9];
  const float* bo = (const float*)d_in[10];
  float* out = (float*)d_out;

  char* ws = (char*)d_ws;
  unsigned short* xb   = (unsigned short*)(ws);               // 32MB  [16384][1024] bf16 (reused as O)
  unsigned short* WTkv = (unsigned short*)(ws + 33554432);    // 4MB   [2048][1024] bf16 (Wk^T ; Wv^T)
  unsigned short* WoT  = (unsigned short*)(ws + 37748736);    // 2MB   [1024][1024] bf16
  unsigned short* kvb  = (unsigned short*)(ws + 39845888);    // 64MB  [16384][2048] bf16

  // chunk-state scratch lives in d_out (64MB f32): fully overwritten by the
  // final GEMM afterwards, so this is free scratch during the wkv phase.
  float* stP = out;                       // 2MB (CCH*NCHAN floats)
  float* stA = out + CCH * NCHAN;         // 2MB
  float* stB = out + 2 * CCH * NCHAN;     // 2MB

  cast_x_kernel<<<dim3(16384), dim3(256), 0, stream>>>(x, xb);
  transpose_cast_kernel<<<dim3(32, 32), dim3(256), 0, stream>>>(Wk, WTkv);
  transpose_cast_kernel<<<dim3(32, 32), dim3(256), 0, stream>>>(Wv, WTkv + 1024 * 1024);
  transpose_cast_kernel<<<dim3(32, 32), dim3(256), 0, stream>>>(Wo, WoT);

  // k|v projection: [16384][1024] @ [1024][2048] -> bf16 kv buffer (+bk|bv)
  gemm_bt_kernel<1><<<dim3(128, 16), dim3(256), 0, stream>>>(
      xb, WTkv, (void*)kvb, bk, bv, MTOT, 2048, 1024, 1024);

  // WKV chunked scan -> O (bf16) into xb (its x-bf16 contents are consumed)
  wkv_chunk_state_kernel<<<dim3(CCH * NB * 512 / 256), dim3(256), 0, stream>>>(
      kvb, wr, stP, stA, stB);
  wkv_scan_kernel<<<dim3(NCHAN / 256), dim3(256), 0, stream>>>(wr, stP, stA, stB);
  wkv_out_kernel<<<dim3(CCH * NB * 512 / 256), dim3(256), 0, stream>>>(
      kvb, wr, ur, stP, stA, stB, xb);

  // output projection: [16384][1024] @ [1024][1024] -> f32 d_out (+bo)
  gemm_bt_kernel<0><<<dim3(128, 8), dim3(256), 0, stream>>>(
      xb, WoT, (void*)out, bo, bo, MTOT, 1024, 1024, 1024);
}

// Round 6
// 182.512 us; speedup vs baseline: 1.2539x; 1.1049x over previous
//
#include <hip/hip_runtime.h>

#define DIMSZ 1024
#define NB 8
#define TSEQ 2048
#define MTOT (NB*TSEQ)   // 16384
#define CCH 64           // chunks per sequence
#define LCH (TSEQ/CCH)   // 32 steps per chunk
#define NCHAN (NB*DIMSZ) // 8192 independent channels

typedef __attribute__((ext_vector_type(8))) short short8v;
typedef __attribute__((ext_vector_type(4))) float f32x4;

__device__ __forceinline__ unsigned short f2bf(float f) {
  unsigned int u; __builtin_memcpy(&u, &f, 4);
  unsigned int r = u + 0x7FFF + ((u >> 16) & 1);   // RNE
  return (unsigned short)(r >> 16);
}
__device__ __forceinline__ float bf2f(unsigned short us) {
  unsigned int v = ((unsigned int)us) << 16;
  float f; __builtin_memcpy(&f, &v, 4); return f;
}

// async global->LDS, 16B per lane; LDS dest is wave-uniform base + lane*16
__device__ __forceinline__ void gload16(const void* g, void* l) {
  __builtin_amdgcn_global_load_lds(
      (const __attribute__((address_space(1))) void*)g,
      (__attribute__((address_space(3))) void*)l, 16, 0, 0);
}

// ---------------- cast x (f32) -> bf16, 4 elems/thread ----------------
__global__ __launch_bounds__(256) void cast_x_kernel(
    const float* __restrict__ in, unsigned short* __restrict__ out) {
  int i = blockIdx.x * 256 + threadIdx.x;
  float4 f = reinterpret_cast<const float4*>(in)[i];
  uint2 o;
  o.x = (unsigned)f2bf(f.x) | ((unsigned)f2bf(f.y) << 16);
  o.y = (unsigned)f2bf(f.z) | ((unsigned)f2bf(f.w) << 16);
  reinterpret_cast<uint2*>(out)[i] = o;
}

// ---------------- transpose + cast W [K][N] f32 -> WT [N][K] bf16 ----------------
__global__ __launch_bounds__(256) void transpose_cast_kernel(
    const float* __restrict__ W, unsigned short* __restrict__ WT) {
  __shared__ float tile[32][33];
  int tx = threadIdx.x & 31, ty = threadIdx.x >> 5;   // 32 x 8
  int row0 = blockIdx.y * 32, col0 = blockIdx.x * 32;
  #pragma unroll
  for (int j = 0; j < 32; j += 8)
    tile[ty + j][tx] = W[(size_t)(row0 + ty + j) * DIMSZ + col0 + tx];
  __syncthreads();
  #pragma unroll
  for (int j = 0; j < 32; j += 8)
    WT[(size_t)(col0 + ty + j) * DIMSZ + row0 + tx] = f2bf(tile[tx][ty + j]);
}

// =============== 256x256 8-phase bf16 MFMA GEMM (T2+T3+T4+T5) ===============
// 512 thr = 8 waves (2M x 4N), per-wave C 128x64 (8x4 16x16 frags), BK=64.
// LDS: 2 K-tile buffers x (A 256x64 + B 256x64) bf16 = 128 KiB (dynamic).
// Effective LDS layout byte(row,cb)=row*128+(cb^((row&7)<<4)) via pre-swizzled
// global source (linear gload_lds dest) + same XOR on ds_read (R4: conflicts=0).
// Phase (mh,nh): 12 ds_read_b128 + stage 1 half-tile (2 gload/wave) + counted
// vmcnt + s_barrier + 16 MFMA (setprio). Stage order A0,B0,B1,A1; waits
// vmcnt(4) @ph0,1,3; epilogue 4->2->0. Never vmcnt(0) in main loop.

#define VM4 asm volatile("s_waitcnt vmcnt(4)" ::: "memory")
#define VM2 asm volatile("s_waitcnt vmcnt(2)" ::: "memory")
#define VM0 asm volatile("s_waitcnt vmcnt(0)" ::: "memory")
#define VMNONE (void)0

// stage one 128-row half-tile of operand OP (0=A,1=B), half HALF, K-tile T
// into buffer BUF. Each wave: 2 gload (rows wid*16..+15 of the half).
#define STAGE(BUF, OP, HALF, T) do {                                        \
  const unsigned short* _s = (OP) ? BT : Aop;                               \
  const int _rb = ((OP) ? bcol : brow) + (HALF)*128 + wid*16;               \
  char* _lb = smem + (BUF)*65536 + (OP)*32768 + ((HALF)*128 + wid*16)*128;  \
  const size_t _k0 = (size_t)(T)*64;                                        \
  gload16(&_s[(size_t)(_rb + srow)*K + _k0 + (sg^srow)*8], _lb);            \
  gload16(&_s[(size_t)(_rb + 8 + srow)*K + _k0 + (sg^srow)*8], _lb + 1024); \
} while(0)

#define PHASE(BUF, MH, NH, STAGE_STMT, VM_STMT) do {                        \
  short8v _af[4][2], _bf[2][2];                                             \
  _Pragma("unroll")                                                         \
  for (int _m = 0; _m < 4; ++_m) {                                          \
    const char* _pa = smem + (BUF)*65536 +                                  \
        ((MH)*128 + wr*64 + _m*16 + lrow)*128;                              \
    _af[_m][0] = *(const short8v*)(_pa + ((lko*2) ^ rds));                  \
    _af[_m][1] = *(const short8v*)(_pa + (((32+lko)*2) ^ rds));             \
  }                                                                         \
  _Pragma("unroll")                                                         \
  for (int _n = 0; _n < 2; ++_n) {                                          \
    const char* _pb = smem + (BUF)*65536 + 32768 +                          \
        ((NH)*128 + wc*32 + _n*16 + lrow)*128;                              \
    _bf[_n][0] = *(const short8v*)(_pb + ((lko*2) ^ rds));                  \
    _bf[_n][1] = *(const short8v*)(_pb + (((32+lko)*2) ^ rds));             \
  }                                                                         \
  STAGE_STMT;                                                               \
  VM_STMT;                                                                  \
  __builtin_amdgcn_s_barrier();                                             \
  __builtin_amdgcn_sched_barrier(0);                                        \
  __builtin_amdgcn_s_setprio(1);                                            \
  _Pragma("unroll")                                                         \
  for (int _m = 0; _m < 4; ++_m)                                            \
    _Pragma("unroll")                                                       \
    for (int _n = 0; _n < 2; ++_n) {                                        \
      acc[(MH)*4+_m][(NH)*2+_n] = __builtin_amdgcn_mfma_f32_16x16x32_bf16(  \
          _af[_m][0], _bf[_n][0], acc[(MH)*4+_m][(NH)*2+_n], 0, 0, 0);      \
      acc[(MH)*4+_m][(NH)*2+_n] = __builtin_amdgcn_mfma_f32_16x16x32_bf16(  \
          _af[_m][1], _bf[_n][1], acc[(MH)*4+_m][(NH)*2+_n], 0, 0, 0);      \
    }                                                                       \
  __builtin_amdgcn_s_setprio(0);                                            \
  __builtin_amdgcn_s_barrier();                                             \
  __builtin_amdgcn_sched_barrier(0);                                        \
} while(0)

template<int OUTBF>
__global__ __launch_bounds__(512) void gemm256_kernel(
    const unsigned short* __restrict__ Aop,
    const unsigned short* __restrict__ BT,
    void* __restrict__ Cv,
    const float* __restrict__ bias0,
    const float* __restrict__ bias1,
    int M, int N, int K, int Nsplit) {
  extern __shared__ char smem[];
  const int tid  = threadIdx.x;
  const int wid  = tid >> 6;          // 0..7
  const int lane = tid & 63;
  const int wr   = wid >> 2;          // 0..1  (M-warps)
  const int wc   = wid & 3;           // 0..3  (N-warps)
  const int brow = blockIdx.x * 256;
  const int bcol = blockIdx.y * 256;
  const int lrow = lane & 15;
  const int lko  = (lane >> 4) * 8;   // elems
  const int rds  = (lrow & 7) << 4;   // read-side XOR (bytes)
  const int srow = lane >> 3;         // staging row in 8-row group
  const int sg   = lane & 7;          // staging granule

  f32x4 acc[8][4];
  #pragma unroll
  for (int m = 0; m < 8; ++m)
    #pragma unroll
    for (int n = 0; n < 4; ++n)
      acc[m][n] = (f32x4){0.f, 0.f, 0.f, 0.f};

  // prologue: stage tile 0 (A0,B0,B1,A1), publish A0+B0
  STAGE(0, 0, 0, 0);
  STAGE(0, 1, 0, 0);
  STAGE(0, 1, 1, 0);
  STAGE(0, 0, 1, 0);
  VM4;
  __builtin_amdgcn_s_barrier();
  __builtin_amdgcn_sched_barrier(0);

  const int NT = K >> 6;
  for (int t = 0; t < NT - 1; ++t) {
    const int b = t & 1, nb = b ^ 1;
    PHASE(b, 0, 0, STAGE(nb, 0, 0, t + 1), VM4);     // stage (t+1).A0
    PHASE(b, 0, 1, STAGE(nb, 1, 0, t + 1), VM4);     // stage (t+1).B0
    PHASE(b, 1, 0, STAGE(nb, 1, 1, t + 1), VMNONE);  // stage (t+1).B1
    PHASE(b, 1, 1, STAGE(nb, 0, 1, t + 1), VM4);     // stage (t+1).A1
  }
  {
    const int b = (NT - 1) & 1;
    PHASE(b, 0, 0, VMNONE, VM2);
    PHASE(b, 0, 1, VMNONE, VM0);
    PHASE(b, 1, 0, VMNONE, VMNONE);
    PHASE(b, 1, 1, VMNONE, VMNONE);
  }

  // epilogue: C write (+bias), scalar stores (16-lane 32B segments)
  #pragma unroll
  for (int mf = 0; mf < 8; ++mf) {
    const int rowb = brow + (mf >= 4) * 128 + wr * 64 + (mf & 3) * 16 + (lane >> 4) * 4;
    #pragma unroll
    for (int nf = 0; nf < 4; ++nf) {
      const int col = bcol + (nf >= 2) * 128 + wc * 32 + (nf & 1) * 16 + lrow;
      const float bb = (col < Nsplit) ? bias0[col] : bias1[col - Nsplit];
      #pragma unroll
      for (int r = 0; r < 4; ++r) {
        const float val = acc[mf][nf][r] + bb;
        if (OUTBF) {
          ((unsigned short*)Cv)[(size_t)(rowb + r) * N + col] = f2bf(val);
        } else {
          ((float*)Cv)[(size_t)(rowb + r) * N + col] = val;
        }
      }
    }
  }
}

// =================== WKV chunked parallel scan ===================
// State (p,a,b): A = a*e^p, B = b*e^p. Empty state (p=-1e30,a=b=0) reproduces
// the reference init and O[0]=v[0] through the uniform step rule.

__device__ __forceinline__ void wkv_step(float& p, float& a, float& b,
                                         float kt, float vt, float w) {
  float ww2 = p - w;
  float qq2 = fmaxf(ww2, kt);
  float e1 = __expf(ww2 - qq2);
  float e2 = __expf(kt - qq2);
  a = e1 * a + e2 * vt;
  b = e1 * b + e2;
  p = qq2;
}

// Pass 1: per-(chunk, channel-pair) local state from empty. 2 channels/thread.
__global__ __launch_bounds__(256) void wkv_chunk_state_kernel(
    const unsigned short* __restrict__ kv,
    const float* __restrict__ wdec,
    float* __restrict__ stP, float* __restrict__ stA, float* __restrict__ stB) {
  int idx = blockIdx.x * 256 + threadIdx.x;     // 0 .. CCH*NB*512-1
  int cp = idx & 511;
  int n = (idx >> 9) & (NB - 1);
  int chunk = idx >> 12;
  int c = cp * 2;
  float2 w2 = *reinterpret_cast<const float2*>(&wdec[c]);
  const unsigned short* base = kv + (size_t)(n * TSEQ + chunk * LCH) * 2048 + c;
  float p0 = -1e30f, a0 = 0.f, b0 = 0.f;
  float p1 = -1e30f, a1 = 0.f, b1 = 0.f;
  #pragma unroll 8
  for (int j = 0; j < LCH; ++j) {
    unsigned int kk = *reinterpret_cast<const unsigned int*>(&base[(size_t)j * 2048]);
    unsigned int vv = *reinterpret_cast<const unsigned int*>(&base[(size_t)j * 2048 + 1024]);
    wkv_step(p0, a0, b0, bf2f(kk & 0xffff), bf2f(vv & 0xffff), w2.x);
    wkv_step(p1, a1, b1, bf2f(kk >> 16),    bf2f(vv >> 16),    w2.y);
  }
  int soff = chunk * NCHAN + n * 1024 + c;
  *reinterpret_cast<float2*>(&stP[soff]) = make_float2(p0, p1);
  *reinterpret_cast<float2*>(&stA[soff]) = make_float2(a0, a1);
  *reinterpret_cast<float2*>(&stB[soff]) = make_float2(b0, b1);
}

// Pass 2: serial scan over chunk states per channel -> incoming prefixes.
__global__ __launch_bounds__(256) void wkv_scan_kernel(
    const float* __restrict__ wdec,
    float* __restrict__ stP, float* __restrict__ stA, float* __restrict__ stB) {
  int idx = blockIdx.x * 256 + threadIdx.x;   // [n][c]
  int c = idx & 1023;
  float decay = (float)LCH * wdec[c];
  float p = -1e30f, a = 0.f, b = 0.f;
  for (int i = 0; i < CCH; ++i) {
    int off = i * NCHAN + idx;
    float pc = stP[off], ac = stA[off], bc = stB[off];
    stP[off] = p; stA[off] = a; stB[off] = b;   // incoming prefix
    float pd = p - decay;
    float q = fmaxf(pd, pc);
    float e1 = __expf(pd - q);
    float e2 = __expf(pc - q);
    a = e1 * a + e2 * ac;
    b = e1 * b + e2 * bc;
    p = q;
  }
}

// Pass 3: replay each chunk from its incoming prefix, emitting outputs. 2 ch/thread.
__global__ __launch_bounds__(256) void wkv_out_kernel(
    const unsigned short* __restrict__ kv,
    const float* __restrict__ wdec, const float* __restrict__ ubon,
    const float* __restrict__ stP, const float* __restrict__ stA,
    const float* __restrict__ stB,
    unsigned short* __restrict__ O) {
  int idx = blockIdx.x * 256 + threadIdx.x;
  int cp = idx & 511;
  int n = (idx >> 9) & (NB - 1);
  int chunk = idx >> 12;
  int c = cp * 2;
  float2 w2 = *reinterpret_cast<const float2*>(&wdec[c]);
  float2 u2 = *reinterpret_cast<const float2*>(&ubon[c]);
  const unsigned short* base = kv + (size_t)(n * TSEQ + chunk * LCH) * 2048 + c;
  unsigned short* ob = O + (size_t)(n * TSEQ + chunk * LCH) * DIMSZ + c;
  int soff = chunk * NCHAN + n * 1024 + c;
  float2 pP = *reinterpret_cast<const float2*>(&stP[soff]);
  float2 pA = *reinterpret_cast<const float2*>(&stA[soff]);
  float2 pB = *reinterpret_cast<const float2*>(&stB[soff]);
  float p0 = pP.x, a0 = pA.x, b0 = pB.x;
  float p1 = pP.y, a1 = pA.y, b1 = pB.y;
  #pragma unroll 4
  for (int j = 0; j < LCH; ++j) {
    unsigned int kk = *reinterpret_cast<const unsigned int*>(&base[(size_t)j * 2048]);
    unsigned int vv = *reinterpret_cast<const unsigned int*>(&base[(size_t)j * 2048 + 1024]);
    float k0 = bf2f(kk & 0xffff), k1 = bf2f(kk >> 16);
    float v0 = bf2f(vv & 0xffff), v1 = bf2f(vv >> 16);
    // outputs from incoming state (bonus u)
    float ww0 = u2.x + k0, ww1 = u2.y + k1;
    float qq0 = fmaxf(ww0, p0), qq1 = fmaxf(ww1, p1);
    float e10 = __expf(p0 - qq0), e20 = __expf(ww0 - qq0);
    float e11 = __expf(p1 - qq1), e21 = __expf(ww1 - qq1);
    float o0 = (e10 * a0 + e20 * v0) * __builtin_amdgcn_rcpf(e10 * b0 + e20);
    float o1 = (e11 * a1 + e21 * v1) * __builtin_amdgcn_rcpf(e11 * b1 + e21);
    *reinterpret_cast<unsigned int*>(&ob[(size_t)j * DIMSZ]) =
        (unsigned)f2bf(o0) | ((unsigned)f2bf(o1) << 16);
    // state update (decay w)
    wkv_step(p0, a0, b0, k0, v0, w2.x);
    wkv_step(p1, a1, b1, k1, v1, w2.y);
  }
}

extern "C" void kernel_launch(void* const* d_in, const int* in_sizes, int n_in,
                              void* d_out, int out_size, void* d_ws, size_t ws_size,
                              hipStream_t stream) {
  const float* x  = (const float*)d_in[0];
  // d_in[1]=Wq, d_in[2]=bq: unused by the reference forward
  const float* Wk = (const float*)d_in[3];
  const float* bk = (const float*)d_in[4];
  const float* Wv = (const float*)d_in[5];
  const float* bv = (const float*)d_in[6];
  const float* wr = (const float*)d_in[7];
  const float* ur = (const float*)d_in[8];
  const float* Wo = (const float*)d_in[9];
  const float* bo = (const float*)d_in[10];
  float* out = (float*)d_out;

  char* ws = (char*)d_ws;
  unsigned short* xb   = (unsigned short*)(ws);               // 32MB  [16384][1024] bf16 (reused as O)
  unsigned short* WTkv = (unsigned short*)(ws + 33554432);    // 4MB   [2048][1024] bf16 (Wk^T ; Wv^T)
  unsigned short* WoT  = (unsigned short*)(ws + 37748736);    // 2MB   [1024][1024] bf16
  unsigned short* kvb  = (unsigned short*)(ws + 39845888);    // 64MB  [16384][2048] bf16

  // chunk-state scratch lives in d_out (64MB f32): fully overwritten by the
  // final GEMM afterwards, so this is free scratch during the wkv phase.
  float* stP = out;                       // 2MB (CCH*NCHAN floats)
  float* stA = out + CCH * NCHAN;         // 2MB
  float* stB = out + 2 * CCH * NCHAN;     // 2MB

  cast_x_kernel<<<dim3(16384), dim3(256), 0, stream>>>(x, xb);
  transpose_cast_kernel<<<dim3(32, 32), dim3(256), 0, stream>>>(Wk, WTkv);
  transpose_cast_kernel<<<dim3(32, 32), dim3(256), 0, stream>>>(Wv, WTkv + 1024 * 1024);
  transpose_cast_kernel<<<dim3(32, 32), dim3(256), 0, stream>>>(Wo, WoT);

  // k|v projection: [16384][1024] @ [1024][2048] -> bf16 kv buffer (+bk|bv)
  gemm256_kernel<1><<<dim3(64, 8), dim3(512), 131072, stream>>>(
      xb, WTkv, (void*)kvb, bk, bv, MTOT, 2048, 1024, 1024);

  // WKV chunked scan -> O (bf16) into xb (its x-bf16 contents are consumed)
  wkv_chunk_state_kernel<<<dim3(CCH * NB * 512 / 256), dim3(256), 0, stream>>>(
      kvb, wr, stP, stA, stB);
  wkv_scan_kernel<<<dim3(NCHAN / 256), dim3(256), 0, stream>>>(wr, stP, stA, stB);
  wkv_out_kernel<<<dim3(CCH * NB * 512 / 256), dim3(256), 0, stream>>>(
      kvb, wr, ur, stP, stA, stB, xb);

  // output projection: [16384][1024] @ [1024][1024] -> f32 d_out (+bo)
  gemm256_kernel<0><<<dim3(64, 4), dim3(512), 131072, stream>>>(
      xb, WoT, (void*)out, bo, bo, MTOT, 1024, 1024, 1024);
}

// Round 7
// 169.543 us; speedup vs baseline: 1.3498x; 1.0765x over previous
//
#include <hip/hip_runtime.h>

#define DIMSZ 1024
#define NB 8
#define TSEQ 2048
#define MTOT (NB*TSEQ)   // 16384
#define CCH 64           // chunks per sequence
#define LCH (TSEQ/CCH)   // 32 steps per chunk
#define NCHAN (NB*DIMSZ) // 8192 independent channels

typedef __attribute__((ext_vector_type(8))) short short8v;
typedef __attribute__((ext_vector_type(4))) float f32x4;

__device__ __forceinline__ unsigned short f2bf(float f) {
  unsigned int u; __builtin_memcpy(&u, &f, 4);
  unsigned int r = u + 0x7FFF + ((u >> 16) & 1);   // RNE
  return (unsigned short)(r >> 16);
}
__device__ __forceinline__ float bf2f(unsigned short us) {
  unsigned int v = ((unsigned int)us) << 16;
  float f; __builtin_memcpy(&f, &v, 4); return f;
}

// async global->LDS, 16B per lane; LDS dest is wave-uniform base + lane*16
__device__ __forceinline__ void gload16(const void* g, void* l) {
  __builtin_amdgcn_global_load_lds(
      (const __attribute__((address_space(1))) void*)g,
      (__attribute__((address_space(3))) void*)l, 16, 0, 0);
}

// ---------------- cast x (f32) -> bf16, 4 elems/thread ----------------
__global__ __launch_bounds__(256) void cast_x_kernel(
    const float* __restrict__ in, unsigned short* __restrict__ out) {
  int i = blockIdx.x * 256 + threadIdx.x;
  float4 f = reinterpret_cast<const float4*>(in)[i];
  uint2 o;
  o.x = (unsigned)f2bf(f.x) | ((unsigned)f2bf(f.y) << 16);
  o.y = (unsigned)f2bf(f.z) | ((unsigned)f2bf(f.w) << 16);
  reinterpret_cast<uint2*>(out)[i] = o;
}

// ---------------- transpose + cast W [K][N] f32 -> WT [N][K] bf16 ----------------
__global__ __launch_bounds__(256) void transpose_cast_kernel(
    const float* __restrict__ W, unsigned short* __restrict__ WT) {
  __shared__ float tile[32][33];
  int tx = threadIdx.x & 31, ty = threadIdx.x >> 5;   // 32 x 8
  int row0 = blockIdx.y * 32, col0 = blockIdx.x * 32;
  #pragma unroll
  for (int j = 0; j < 32; j += 8)
    tile[ty + j][tx] = W[(size_t)(row0 + ty + j) * DIMSZ + col0 + tx];
  __syncthreads();
  #pragma unroll
  for (int j = 0; j < 32; j += 8)
    WT[(size_t)(col0 + ty + j) * DIMSZ + row0 + tx] = f2bf(tile[tx][ty + j]);
}

// =============== 256x256 8-phase bf16 MFMA GEMM (T2+T3+T4+T5) ===============
// 512 thr = 8 waves (2M x 4N), per-wave C 128x64 (8x4 16x16 frags), BK=64.
// LDS: 2 K-tile buffers x (A 256x64 + B 256x64) bf16 = 128 KiB (dynamic).
// Effective LDS layout byte(row,cb)=row*128+(cb^((row&7)<<4)) via pre-swizzled
// global source (linear gload_lds dest) + same XOR on ds_read (conflicts=0).
// R6 fix: fragments are read ONCE per K-tile and HELD across phases
// (a0@ph0, b0@ph0, b1@ph1, a1@ph2; ph3 reads nothing) -> 24 ds_read_b128
// per wave per K-tile (was 48, which oversubscribed LDS read BW ~1.9x).
// Stage order A0,B0,B1,A1; counted waits vmcnt(4) @ph0,1,3; never vmcnt(0)
// in the main loop; epilogue drains 4->2->0.

#define VM4 asm volatile("s_waitcnt vmcnt(4)" ::: "memory")
#define VM2 asm volatile("s_waitcnt vmcnt(2)" ::: "memory")
#define VM0 asm volatile("s_waitcnt vmcnt(0)" ::: "memory")

#define PH_BAR do {                         \
  __builtin_amdgcn_s_barrier();             \
  __builtin_amdgcn_sched_barrier(0);        \
} while(0)

// stage one 128-row half-tile of operand OP (0=A,1=B), half HALF, K-tile T
// into buffer BUF. Each wave: 2 gload (rows wid*16..+15 of the half).
#define STAGE(BUF, OP, HALF, T) do {                                        \
  const unsigned short* _s = (OP) ? BT : Aop;                               \
  const int _rb = ((OP) ? bcol : brow) + (HALF)*128 + wid*16;               \
  char* _lb = smem + (BUF)*65536 + (OP)*32768 + ((HALF)*128 + wid*16)*128;  \
  const size_t _k0 = (size_t)(T)*64;                                        \
  gload16(&_s[(size_t)(_rb + srow)*K + _k0 + (sg^srow)*8], _lb);            \
  gload16(&_s[(size_t)(_rb + 8 + srow)*K + _k0 + (sg^srow)*8], _lb + 1024); \
} while(0)

#define READ_A(DST, BUF, MH) do {                                           \
  _Pragma("unroll")                                                         \
  for (int _m = 0; _m < 4; ++_m) {                                          \
    const char* _pa = smem + (BUF)*65536 +                                  \
        ((MH)*128 + wr*64 + _m*16 + lrow)*128;                              \
    DST[_m][0] = *(const short8v*)(_pa + ((lko*2) ^ rds));                  \
    DST[_m][1] = *(const short8v*)(_pa + (((32+lko)*2) ^ rds));             \
  }                                                                         \
} while(0)

#define READ_B(DST, BUF, NH) do {                                           \
  _Pragma("unroll")                                                         \
  for (int _n = 0; _n < 2; ++_n) {                                          \
    const char* _pb = smem + (BUF)*65536 + 32768 +                          \
        ((NH)*128 + wc*32 + _n*16 + lrow)*128;                              \
    DST[_n][0] = *(const short8v*)(_pb + ((lko*2) ^ rds));                  \
    DST[_n][1] = *(const short8v*)(_pb + (((32+lko)*2) ^ rds));             \
  }                                                                         \
} while(0)

#define MFMA_Q(MH, NH, AF, BF) do {                                         \
  __builtin_amdgcn_s_setprio(1);                                            \
  _Pragma("unroll")                                                         \
  for (int _m = 0; _m < 4; ++_m)                                            \
    _Pragma("unroll")                                                       \
    for (int _n = 0; _n < 2; ++_n) {                                        \
      acc[(MH)*4+_m][(NH)*2+_n] = __builtin_amdgcn_mfma_f32_16x16x32_bf16(  \
          AF[_m][0], BF[_n][0], acc[(MH)*4+_m][(NH)*2+_n], 0, 0, 0);        \
      acc[(MH)*4+_m][(NH)*2+_n] = __builtin_amdgcn_mfma_f32_16x16x32_bf16(  \
          AF[_m][1], BF[_n][1], acc[(MH)*4+_m][(NH)*2+_n], 0, 0, 0);        \
    }                                                                       \
  __builtin_amdgcn_s_setprio(0);                                            \
  PH_BAR;                                                                   \
} while(0)

template<int OUTBF>
__global__ __launch_bounds__(512) void gemm256_kernel(
    const unsigned short* __restrict__ Aop,
    const unsigned short* __restrict__ BT,
    void* __restrict__ Cv,
    const float* __restrict__ bias0,
    const float* __restrict__ bias1,
    int M, int N, int K, int Nsplit) {
  extern __shared__ char smem[];
  const int tid  = threadIdx.x;
  const int wid  = tid >> 6;          // 0..7
  const int lane = tid & 63;
  const int wr   = wid >> 2;          // 0..1  (M-warps)
  const int wc   = wid & 3;           // 0..3  (N-warps)
  const int brow = blockIdx.x * 256;
  const int bcol = blockIdx.y * 256;
  const int lrow = lane & 15;
  const int lko  = (lane >> 4) * 8;   // elems
  const int rds  = (lrow & 7) << 4;   // read-side XOR (bytes)
  const int srow = lane >> 3;         // staging row in 8-row group
  const int sg   = lane & 7;          // staging granule

  f32x4 acc[8][4];
  #pragma unroll
  for (int m = 0; m < 8; ++m)
    #pragma unroll
    for (int n = 0; n < 4; ++n)
      acc[m][n] = (f32x4){0.f, 0.f, 0.f, 0.f};

  // prologue: stage tile 0 (A0,B0,B1,A1), publish A0+B0
  STAGE(0, 0, 0, 0);
  STAGE(0, 1, 0, 0);
  STAGE(0, 1, 1, 0);
  STAGE(0, 0, 1, 0);
  VM4;
  PH_BAR;

  const int NT = K >> 6;
  short8v a0[4][2], a1[4][2], bf0[2][2], bf1[2][2];
  for (int t = 0; t < NT - 1; ++t) {
    const int b = t & 1, nb = b ^ 1;
    // phase 0: read a0,b0; stage (t+1).A0
    READ_A(a0, b, 0); READ_B(bf0, b, 0);
    STAGE(nb, 0, 0, t + 1); VM4; PH_BAR;
    MFMA_Q(0, 0, a0, bf0);
    // phase 1: read b1; stage (t+1).B0
    READ_B(bf1, b, 1);
    STAGE(nb, 1, 0, t + 1); VM4; PH_BAR;
    MFMA_Q(0, 1, a0, bf1);
    // phase 2: read a1; stage (t+1).B1
    READ_A(a1, b, 1);
    STAGE(nb, 1, 1, t + 1); PH_BAR;
    MFMA_Q(1, 0, a1, bf0);
    // phase 3: no reads; stage (t+1).A1
    STAGE(nb, 0, 1, t + 1); VM4; PH_BAR;
    MFMA_Q(1, 1, a1, bf1);
  }
  {
    const int b = (NT - 1) & 1;
    READ_A(a0, b, 0); READ_B(bf0, b, 0);
    VM2; PH_BAR;
    MFMA_Q(0, 0, a0, bf0);
    READ_B(bf1, b, 1);
    VM0; PH_BAR;
    MFMA_Q(0, 1, a0, bf1);
    READ_A(a1, b, 1);
    PH_BAR;
    MFMA_Q(1, 0, a1, bf0);
    PH_BAR;
    MFMA_Q(1, 1, a1, bf1);
  }

  // epilogue: C write (+bias)
  #pragma unroll
  for (int mf = 0; mf < 8; ++mf) {
    const int rowb = brow + (mf >= 4) * 128 + wr * 64 + (mf & 3) * 16 + (lane >> 4) * 4;
    #pragma unroll
    for (int nf = 0; nf < 4; ++nf) {
      const int col = bcol + (nf >= 2) * 128 + wc * 32 + (nf & 1) * 16 + lrow;
      const float bb = (col < Nsplit) ? bias0[col] : bias1[col - Nsplit];
      #pragma unroll
      for (int r = 0; r < 4; ++r) {
        const float val = acc[mf][nf][r] + bb;
        if (OUTBF) {
          ((unsigned short*)Cv)[(size_t)(rowb + r) * N + col] = f2bf(val);
        } else {
          ((float*)Cv)[(size_t)(rowb + r) * N + col] = val;
        }
      }
    }
  }
}

// =================== WKV chunked parallel scan ===================
// State (p,a,b): A = a*e^p, B = b*e^p. Empty state (p=-1e30,a=b=0) reproduces
// the reference init and O[0]=v[0] through the uniform step rule.

__device__ __forceinline__ void wkv_step(float& p, float& a, float& b,
                                         float kt, float vt, float w) {
  float ww2 = p - w;
  float qq2 = fmaxf(ww2, kt);
  float e1 = __expf(ww2 - qq2);
  float e2 = __expf(kt - qq2);
  a = e1 * a + e2 * vt;
  b = e1 * b + e2;
  p = qq2;
}

// Pass 1: per-(chunk, channel-pair) local state from empty. 2 channels/thread.
__global__ __launch_bounds__(256) void wkv_chunk_state_kernel(
    const unsigned short* __restrict__ kv,
    const float* __restrict__ wdec,
    float* __restrict__ stP, float* __restrict__ stA, float* __restrict__ stB) {
  int idx = blockIdx.x * 256 + threadIdx.x;     // 0 .. CCH*NB*512-1
  int cp = idx & 511;
  int n = (idx >> 9) & (NB - 1);
  int chunk = idx >> 12;
  int c = cp * 2;
  float2 w2 = *reinterpret_cast<const float2*>(&wdec[c]);
  const unsigned short* base = kv + (size_t)(n * TSEQ + chunk * LCH) * 2048 + c;
  float p0 = -1e30f, a0 = 0.f, b0 = 0.f;
  float p1 = -1e30f, a1 = 0.f, b1 = 0.f;
  #pragma unroll 8
  for (int j = 0; j < LCH; ++j) {
    unsigned int kk = *reinterpret_cast<const unsigned int*>(&base[(size_t)j * 2048]);
    unsigned int vv = *reinterpret_cast<const unsigned int*>(&base[(size_t)j * 2048 + 1024]);
    wkv_step(p0, a0, b0, bf2f(kk & 0xffff), bf2f(vv & 0xffff), w2.x);
    wkv_step(p1, a1, b1, bf2f(kk >> 16),    bf2f(vv >> 16),    w2.y);
  }
  int soff = chunk * NCHAN + n * 1024 + c;
  *reinterpret_cast<float2*>(&stP[soff]) = make_float2(p0, p1);
  *reinterpret_cast<float2*>(&stA[soff]) = make_float2(a0, a1);
  *reinterpret_cast<float2*>(&stB[soff]) = make_float2(b0, b1);
}

// Pass 2: serial scan over chunk states per channel -> incoming prefixes.
__global__ __launch_bounds__(256) void wkv_scan_kernel(
    const float* __restrict__ wdec,
    float* __restrict__ stP, float* __restrict__ stA, float* __restrict__ stB) {
  int idx = blockIdx.x * 256 + threadIdx.x;   // [n][c]
  int c = idx & 1023;
  float decay = (float)LCH * wdec[c];
  float p = -1e30f, a = 0.f, b = 0.f;
  for (int i = 0; i < CCH; ++i) {
    int off = i * NCHAN + idx;
    float pc = stP[off], ac = stA[off], bc = stB[off];
    stP[off] = p; stA[off] = a; stB[off] = b;   // incoming prefix
    float pd = p - decay;
    float q = fmaxf(pd, pc);
    float e1 = __expf(pd - q);
    float e2 = __expf(pc - q);
    a = e1 * a + e2 * ac;
    b = e1 * b + e2 * bc;
    p = q;
  }
}

// Pass 3: replay each chunk from its incoming prefix, emitting outputs. 2 ch/thread.
__global__ __launch_bounds__(256) void wkv_out_kernel(
    const unsigned short* __restrict__ kv,
    const float* __restrict__ wdec, const float* __restrict__ ubon,
    const float* __restrict__ stP, const float* __restrict__ stA,
    const float* __restrict__ stB,
    unsigned short* __restrict__ O) {
  int idx = blockIdx.x * 256 + threadIdx.x;
  int cp = idx & 511;
  int n = (idx >> 9) & (NB - 1);
  int chunk = idx >> 12;
  int c = cp * 2;
  float2 w2 = *reinterpret_cast<const float2*>(&wdec[c]);
  float2 u2 = *reinterpret_cast<const float2*>(&ubon[c]);
  const unsigned short* base = kv + (size_t)(n * TSEQ + chunk * LCH) * 2048 + c;
  unsigned short* ob = O + (size_t)(n * TSEQ + chunk * LCH) * DIMSZ + c;
  int soff = chunk * NCHAN + n * 1024 + c;
  float2 pP = *reinterpret_cast<const float2*>(&stP[soff]);
  float2 pA = *reinterpret_cast<const float2*>(&stA[soff]);
  float2 pB = *reinterpret_cast<const float2*>(&stB[soff]);
  float p0 = pP.x, a0 = pA.x, b0 = pB.x;
  float p1 = pP.y, a1 = pA.y, b1 = pB.y;
  #pragma unroll 4
  for (int j = 0; j < LCH; ++j) {
    unsigned int kk = *reinterpret_cast<const unsigned int*>(&base[(size_t)j * 2048]);
    unsigned int vv = *reinterpret_cast<const unsigned int*>(&base[(size_t)j * 2048 + 1024]);
    float k0 = bf2f(kk & 0xffff), k1 = bf2f(kk >> 16);
    float v0 = bf2f(vv & 0xffff), v1 = bf2f(vv >> 16);
    // outputs from incoming state (bonus u)
    float ww0 = u2.x + k0, ww1 = u2.y + k1;
    float qq0 = fmaxf(ww0, p0), qq1 = fmaxf(ww1, p1);
    float e10 = __expf(p0 - qq0), e20 = __expf(ww0 - qq0);
    float e11 = __expf(p1 - qq1), e21 = __expf(ww1 - qq1);
    float o0 = (e10 * a0 + e20 * v0) * __builtin_amdgcn_rcpf(e10 * b0 + e20);
    float o1 = (e11 * a1 + e21 * v1) * __builtin_amdgcn_rcpf(e11 * b1 + e21);
    *reinterpret_cast<unsigned int*>(&ob[(size_t)j * DIMSZ]) =
        (unsigned)f2bf(o0) | ((unsigned)f2bf(o1) << 16);
    // state update (decay w)
    wkv_step(p0, a0, b0, k0, v0, w2.x);
    wkv_step(p1, a1, b1, k1, v1, w2.y);
  }
}

extern "C" void kernel_launch(void* const* d_in, const int* in_sizes, int n_in,
                              void* d_out, int out_size, void* d_ws, size_t ws_size,
                              hipStream_t stream) {
  const float* x  = (const float*)d_in[0];
  // d_in[1]=Wq, d_in[2]=bq: unused by the reference forward
  const float* Wk = (const float*)d_in[3];
  const float* bk = (const float*)d_in[4];
  const float* Wv = (const float*)d_in[5];
  const float* bv = (const float*)d_in[6];
  const float* wr = (const float*)d_in[7];
  const float* ur = (const float*)d_in[8];
  const float* Wo = (const float*)d_in[9];
  const float* bo = (const float*)d_in[10];
  float* out = (float*)d_out;

  char* ws = (char*)d_ws;
  unsigned short* xb   = (unsigned short*)(ws);               // 32MB  [16384][1024] bf16 (reused as O)
  unsigned short* WTkv = (unsigned short*)(ws + 33554432);    // 4MB   [2048][1024] bf16 (Wk^T ; Wv^T)
  unsigned short* WoT  = (unsigned short*)(ws + 37748736);    // 2MB   [1024][1024] bf16
  unsigned short* kvb  = (unsigned short*)(ws + 39845888);    // 64MB  [16384][2048] bf16

  // chunk-state scratch lives in d_out (64MB f32): fully overwritten by the
  // final GEMM afterwards, so this is free scratch during the wkv phase.
  float* stP = out;                       // 2MB (CCH*NCHAN floats)
  float* stA = out + CCH * NCHAN;         // 2MB
  float* stB = out + 2 * CCH * NCHAN;     // 2MB

  cast_x_kernel<<<dim3(16384), dim3(256), 0, stream>>>(x, xb);
  transpose_cast_kernel<<<dim3(32, 32), dim3(256), 0, stream>>>(Wk, WTkv);
  transpose_cast_kernel<<<dim3(32, 32), dim3(256), 0, stream>>>(Wv, WTkv + 1024 * 1024);
  transpose_cast_kernel<<<dim3(32, 32), dim3(256), 0, stream>>>(Wo, WoT);

  // k|v projection: [16384][1024] @ [1024][2048] -> bf16 kv buffer (+bk|bv)
  gemm256_kernel<1><<<dim3(64, 8), dim3(512), 131072, stream>>>(
      xb, WTkv, (void*)kvb, bk, bv, MTOT, 2048, 1024, 1024);

  // WKV chunked scan -> O (bf16) into xb (its x-bf16 contents are consumed)
  wkv_chunk_state_kernel<<<dim3(CCH * NB * 512 / 256), dim3(256), 0, stream>>>(
      kvb, wr, stP, stA, stB);
  wkv_scan_kernel<<<dim3(NCHAN / 256), dim3(256), 0, stream>>>(wr, stP, stA, stB);
  wkv_out_kernel<<<dim3(CCH * NB * 512 / 256), dim3(256), 0, stream>>>(
      kvb, wr, ur, stP, stA, stB, xb);

  // output projection: [16384][1024] @ [1024][1024] -> f32 d_out (+bo)
  gemm256_kernel<0><<<dim3(64, 4), dim3(512), 131072, stream>>>(
      xb, WoT, (void*)out, bo, bo, MTOT, 1024, 1024, 1024);
}

// Round 8
// 169.120 us; speedup vs baseline: 1.3532x; 1.0025x over previous
//
#include <hip/hip_runtime.h>

#define DIMSZ 1024
#define NB 8
#define TSEQ 2048
#define MTOT (NB*TSEQ)   // 16384
#define CCH 64           // chunks per sequence
#define LCH (TSEQ/CCH)   // 32 steps per chunk
#define NCHAN (NB*DIMSZ) // 8192 independent channels

typedef __attribute__((ext_vector_type(8))) short short8v;
typedef __attribute__((ext_vector_type(4))) float f32x4;

__device__ __forceinline__ unsigned short f2bf(float f) {
  unsigned int u; __builtin_memcpy(&u, &f, 4);
  unsigned int r = u + 0x7FFF + ((u >> 16) & 1);   // RNE
  return (unsigned short)(r >> 16);
}
__device__ __forceinline__ float bf2f(unsigned short us) {
  unsigned int v = ((unsigned int)us) << 16;
  float f; __builtin_memcpy(&f, &v, 4); return f;
}

// async global->LDS, 16B per lane; LDS dest is wave-uniform base + lane*16
__device__ __forceinline__ void gload16(const void* g, void* l) {
  __builtin_amdgcn_global_load_lds(
      (const __attribute__((address_space(1))) void*)g,
      (__attribute__((address_space(3))) void*)l, 16, 0, 0);
}

// ---------------- cast x (f32) -> bf16, 4 elems/thread ----------------
__global__ __launch_bounds__(256) void cast_x_kernel(
    const float* __restrict__ in, unsigned short* __restrict__ out) {
  int i = blockIdx.x * 256 + threadIdx.x;
  float4 f = reinterpret_cast<const float4*>(in)[i];
  uint2 o;
  o.x = (unsigned)f2bf(f.x) | ((unsigned)f2bf(f.y) << 16);
  o.y = (unsigned)f2bf(f.z) | ((unsigned)f2bf(f.w) << 16);
  reinterpret_cast<uint2*>(out)[i] = o;
}

// ---------------- transpose + cast W [K][N] f32 -> WT [N][K] bf16 ----------------
__global__ __launch_bounds__(256) void transpose_cast_kernel(
    const float* __restrict__ W, unsigned short* __restrict__ WT) {
  __shared__ float tile[32][33];
  int tx = threadIdx.x & 31, ty = threadIdx.x >> 5;   // 32 x 8
  int row0 = blockIdx.y * 32, col0 = blockIdx.x * 32;
  #pragma unroll
  for (int j = 0; j < 32; j += 8)
    tile[ty + j][tx] = W[(size_t)(row0 + ty + j) * DIMSZ + col0 + tx];
  __syncthreads();
  #pragma unroll
  for (int j = 0; j < 32; j += 8)
    WT[(size_t)(col0 + ty + j) * DIMSZ + row0 + tx] = f2bf(tile[tx][ty + j]);
}

// =============== 256x256 8-phase bf16 MFMA GEMM (T2+T3+T4+T5) ===============
// 512 thr = 8 waves (2M x 4N), per-wave C 128x64 (8x4 16x16 frags), BK=64.
// LDS: 2 K-tile buffers x (A 256x64 + B 256x64) bf16 = 128 KiB (dynamic).
// Effective layout byte(row,cb)=row*128+(cb^((row&7)<<4)) via pre-swizzled
// global source + same XOR on ds_read (conflicts=0, verified R5).
// R7 fix: PHASE-AHEAD register pipelining — ds_reads in phase q feed phase
// q+1's MFMA, so the LDS pipe (578cyc) overlaps the MFMA burst (621cyc)
// instead of serializing. Read schedule: a0,b0(t) @ph3 of t-1; b1(t) @ph0;
// a1(t) @ph1; nothing @ph2. vmcnt: VM2@ph0 (covers A1(t)), none@ph1,
// VM2@ph2 (covers A0,B0(t+1)), VM2@ph3 (covers B1(t+1)). Queue <= 6,
// never vmcnt(0) in main loop.

#define VM2 asm volatile("s_waitcnt vmcnt(2)" ::: "memory")
#define VM0 asm volatile("s_waitcnt vmcnt(0)" ::: "memory")

#define PH_BAR do {                         \
  __builtin_amdgcn_s_barrier();             \
  __builtin_amdgcn_sched_barrier(0);        \
} while(0)

// stage one 128-row half-tile of operand OP (0=A,1=B), half HALF, K-tile T
// into buffer BUF. Each wave: 2 gload (rows wid*16..+15 of the half).
#define STAGE(BUF, OP, HALF, T) do {                                        \
  const unsigned short* _s = (OP) ? BT : Aop;                               \
  const int _rb = ((OP) ? bcol : brow) + (HALF)*128 + wid*16;               \
  char* _lb = smem + (BUF)*65536 + (OP)*32768 + ((HALF)*128 + wid*16)*128;  \
  const size_t _k0 = (size_t)(T)*64;                                        \
  gload16(&_s[(size_t)(_rb + srow)*K + _k0 + (sg^srow)*8], _lb);            \
  gload16(&_s[(size_t)(_rb + 8 + srow)*K + _k0 + (sg^srow)*8], _lb + 1024); \
} while(0)

#define READ_A(DST, BUF, MH) do {                                           \
  _Pragma("unroll")                                                         \
  for (int _m = 0; _m < 4; ++_m) {                                          \
    const char* _pa = smem + (BUF)*65536 +                                  \
        ((MH)*128 + wr*64 + _m*16 + lrow)*128;                              \
    DST[_m][0] = *(const short8v*)(_pa + ((lko*2) ^ rds));                  \
    DST[_m][1] = *(const short8v*)(_pa + (((32+lko)*2) ^ rds));             \
  }                                                                         \
} while(0)

#define READ_B(DST, BUF, NH) do {                                           \
  _Pragma("unroll")                                                         \
  for (int _n = 0; _n < 2; ++_n) {                                          \
    const char* _pb = smem + (BUF)*65536 + 32768 +                          \
        ((NH)*128 + wc*32 + _n*16 + lrow)*128;                              \
    DST[_n][0] = *(const short8v*)(_pb + ((lko*2) ^ rds));                  \
    DST[_n][1] = *(const short8v*)(_pb + (((32+lko)*2) ^ rds));             \
  }                                                                         \
} while(0)

#define MFMA_Q(MH, NH, AF, BF) do {                                         \
  __builtin_amdgcn_s_setprio(1);                                            \
  _Pragma("unroll")                                                         \
  for (int _m = 0; _m < 4; ++_m)                                            \
    _Pragma("unroll")                                                       \
    for (int _n = 0; _n < 2; ++_n) {                                        \
      acc[(MH)*4+_m][(NH)*2+_n] = __builtin_amdgcn_mfma_f32_16x16x32_bf16(  \
          AF[_m][0], BF[_n][0], acc[(MH)*4+_m][(NH)*2+_n], 0, 0, 0);        \
      acc[(MH)*4+_m][(NH)*2+_n] = __builtin_amdgcn_mfma_f32_16x16x32_bf16(  \
          AF[_m][1], BF[_n][1], acc[(MH)*4+_m][(NH)*2+_n], 0, 0, 0);        \
    }                                                                       \
  __builtin_amdgcn_s_setprio(0);                                            \
} while(0)

template<int OUTBF>
__global__ __launch_bounds__(512) void gemm256_kernel(
    const unsigned short* __restrict__ Aop,
    const unsigned short* __restrict__ BT,
    void* __restrict__ Cv,
    const float* __restrict__ bias0,
    const float* __restrict__ bias1,
    int M, int N, int K, int Nsplit) {
  extern __shared__ char smem[];
  const int tid  = threadIdx.x;
  const int wid  = tid >> 6;          // 0..7
  const int lane = tid & 63;
  const int wr   = wid >> 2;          // 0..1  (M-warps)
  const int wc   = wid & 3;           // 0..3  (N-warps)
  const int brow = blockIdx.x * 256;
  const int bcol = blockIdx.y * 256;
  const int lrow = lane & 15;
  const int lko  = (lane >> 4) * 8;   // elems
  const int rds  = (lrow & 7) << 4;   // read-side XOR (bytes)
  const int srow = lane >> 3;         // staging row in 8-row group
  const int sg   = lane & 7;          // staging granule

  f32x4 acc[8][4];
  #pragma unroll
  for (int m = 0; m < 8; ++m)
    #pragma unroll
    for (int n = 0; n < 4; ++n)
      acc[m][n] = (f32x4){0.f, 0.f, 0.f, 0.f};

  short8v a0[4][2], a1[4][2], bf0[2][2], bf1[2][2];

  // prologue: stage tile 0 (A0,B0,B1,A1); publish A0,B0,B1; pre-read a0,b0
  STAGE(0, 0, 0, 0);
  STAGE(0, 1, 0, 0);
  STAGE(0, 1, 1, 0);
  STAGE(0, 0, 1, 0);
  VM2;
  PH_BAR;
  READ_A(a0, 0, 0); READ_B(bf0, 0, 0);

  const int NT = K >> 6;
  for (int t = 0; t < NT - 1; ++t) {
    const int b = t & 1, nb = b ^ 1;
    // ph0: read b1(t); stage (t+1).A0; VM2 covers A1(t)
    READ_B(bf1, b, 1);
    STAGE(nb, 0, 0, t + 1); VM2; PH_BAR;
    MFMA_Q(0, 0, a0, bf0); PH_BAR;
    // ph1: read a1(t); stage (t+1).B0
    READ_A(a1, b, 1);
    STAGE(nb, 1, 0, t + 1); PH_BAR;
    MFMA_Q(0, 1, a0, bf1); PH_BAR;
    // ph2: stage (t+1).B1; VM2 covers A0(t+1),B0(t+1)
    STAGE(nb, 1, 1, t + 1); VM2; PH_BAR;
    MFMA_Q(1, 0, a1, bf0); PH_BAR;
    // ph3: read a0(t+1),b0(t+1) from next buffer; stage (t+1).A1; VM2 covers B1(t+1)
    READ_A(a0, nb, 0); READ_B(bf0, nb, 0);
    STAGE(nb, 0, 1, t + 1); VM2; PH_BAR;
    MFMA_Q(1, 1, a1, bf1); PH_BAR;
  }
  {
    const int b = (NT - 1) & 1;
    READ_B(bf1, b, 1);
    VM0; PH_BAR;              // publish A1(NT-1) (last outstanding)
    MFMA_Q(0, 0, a0, bf0);
    READ_A(a1, b, 1);
    MFMA_Q(0, 1, a0, bf1);
    MFMA_Q(1, 0, a1, bf0);
    MFMA_Q(1, 1, a1, bf1);
  }

  // epilogue: C write (+bias)
  #pragma unroll
  for (int mf = 0; mf < 8; ++mf) {
    const int rowb = brow + (mf >= 4) * 128 + wr * 64 + (mf & 3) * 16 + (lane >> 4) * 4;
    #pragma unroll
    for (int nf = 0; nf < 4; ++nf) {
      const int col = bcol + (nf >= 2) * 128 + wc * 32 + (nf & 1) * 16 + lrow;
      const float bb = (col < Nsplit) ? bias0[col] : bias1[col - Nsplit];
      #pragma unroll
      for (int r = 0; r < 4; ++r) {
        const float val = acc[mf][nf][r] + bb;
        if (OUTBF) {
          ((unsigned short*)Cv)[(size_t)(rowb + r) * N + col] = f2bf(val);
        } else {
          ((float*)Cv)[(size_t)(rowb + r) * N + col] = val;
        }
      }
    }
  }
}

// =================== WKV chunked parallel scan ===================
// State (p,a,b): A = a*e^p, B = b*e^p. Empty state (p=-1e30,a=b=0) reproduces
// the reference init and O[0]=v[0] through the uniform step rule.

__device__ __forceinline__ void wkv_step(float& p, float& a, float& b,
                                         float kt, float vt, float w) {
  float ww2 = p - w;
  float qq2 = fmaxf(ww2, kt);
  float e1 = __expf(ww2 - qq2);
  float e2 = __expf(kt - qq2);
  a = e1 * a + e2 * vt;
  b = e1 * b + e2;
  p = qq2;
}

// Pass 1: per-(chunk, channel-pair) local state from empty. 2 channels/thread.
__global__ __launch_bounds__(256) void wkv_chunk_state_kernel(
    const unsigned short* __restrict__ kv,
    const float* __restrict__ wdec,
    float* __restrict__ stP, float* __restrict__ stA, float* __restrict__ stB) {
  int idx = blockIdx.x * 256 + threadIdx.x;     // 0 .. CCH*NB*512-1
  int cp = idx & 511;
  int n = (idx >> 9) & (NB - 1);
  int chunk = idx >> 12;
  int c = cp * 2;
  float2 w2 = *reinterpret_cast<const float2*>(&wdec[c]);
  const unsigned short* base = kv + (size_t)(n * TSEQ + chunk * LCH) * 2048 + c;
  float p0 = -1e30f, a0 = 0.f, b0 = 0.f;
  float p1 = -1e30f, a1 = 0.f, b1 = 0.f;
  #pragma unroll 8
  for (int j = 0; j < LCH; ++j) {
    unsigned int kk = *reinterpret_cast<const unsigned int*>(&base[(size_t)j * 2048]);
    unsigned int vv = *reinterpret_cast<const unsigned int*>(&base[(size_t)j * 2048 + 1024]);
    wkv_step(p0, a0, b0, bf2f(kk & 0xffff), bf2f(vv & 0xffff), w2.x);
    wkv_step(p1, a1, b1, bf2f(kk >> 16),    bf2f(vv >> 16),    w2.y);
  }
  int soff = chunk * NCHAN + n * 1024 + c;
  *reinterpret_cast<float2*>(&stP[soff]) = make_float2(p0, p1);
  *reinterpret_cast<float2*>(&stA[soff]) = make_float2(a0, a1);
  *reinterpret_cast<float2*>(&stB[soff]) = make_float2(b0, b1);
}

// Pass 2: serial scan over chunk states per channel -> incoming prefixes.
__global__ __launch_bounds__(256) void wkv_scan_kernel(
    const float* __restrict__ wdec,
    float* __restrict__ stP, float* __restrict__ stA, float* __restrict__ stB) {
  int idx = blockIdx.x * 256 + threadIdx.x;   // [n][c]
  int c = idx & 1023;
  float decay = (float)LCH * wdec[c];
  float p = -1e30f, a = 0.f, b = 0.f;
  for (int i = 0; i < CCH; ++i) {
    int off = i * NCHAN + idx;
    float pc = stP[off], ac = stA[off], bc = stB[off];
    stP[off] = p; stA[off] = a; stB[off] = b;   // incoming prefix
    float pd = p - decay;
    float q = fmaxf(pd, pc);
    float e1 = __expf(pd - q);
    float e2 = __expf(pc - q);
    a = e1 * a + e2 * ac;
    b = e1 * b + e2 * bc;
    p = q;
  }
}

// Pass 3: replay each chunk from its incoming prefix, emitting outputs. 2 ch/thread.
__global__ __launch_bounds__(256) void wkv_out_kernel(
    const unsigned short* __restrict__ kv,
    const float* __restrict__ wdec, const float* __restrict__ ubon,
    const float* __restrict__ stP, const float* __restrict__ stA,
    const float* __restrict__ stB,
    unsigned short* __restrict__ O) {
  int idx = blockIdx.x * 256 + threadIdx.x;
  int cp = idx & 511;
  int n = (idx >> 9) & (NB - 1);
  int chunk = idx >> 12;
  int c = cp * 2;
  float2 w2 = *reinterpret_cast<const float2*>(&wdec[c]);
  float2 u2 = *reinterpret_cast<const float2*>(&ubon[c]);
  const unsigned short* base = kv + (size_t)(n * TSEQ + chunk * LCH) * 2048 + c;
  unsigned short* ob = O + (size_t)(n * TSEQ + chunk * LCH) * DIMSZ + c;
  int soff = chunk * NCHAN + n * 1024 + c;
  float2 pP = *reinterpret_cast<const float2*>(&stP[soff]);
  float2 pA = *reinterpret_cast<const float2*>(&stA[soff]);
  float2 pB = *reinterpret_cast<const float2*>(&stB[soff]);
  float p0 = pP.x, a0 = pA.x, b0 = pB.x;
  float p1 = pP.y, a1 = pA.y, b1 = pB.y;
  #pragma unroll 4
  for (int j = 0; j < LCH; ++j) {
    unsigned int kk = *reinterpret_cast<const unsigned int*>(&base[(size_t)j * 2048]);
    unsigned int vv = *reinterpret_cast<const unsigned int*>(&base[(size_t)j * 2048 + 1024]);
    float k0 = bf2f(kk & 0xffff), k1 = bf2f(kk >> 16);
    float v0 = bf2f(vv & 0xffff), v1 = bf2f(vv >> 16);
    // outputs from incoming state (bonus u)
    float ww0 = u2.x + k0, ww1 = u2.y + k1;
    float qq0 = fmaxf(ww0, p0), qq1 = fmaxf(ww1, p1);
    float e10 = __expf(p0 - qq0), e20 = __expf(ww0 - qq0);
    float e11 = __expf(p1 - qq1), e21 = __expf(ww1 - qq1);
    float o0 = (e10 * a0 + e20 * v0) * __builtin_amdgcn_rcpf(e10 * b0 + e20);
    float o1 = (e11 * a1 + e21 * v1) * __builtin_amdgcn_rcpf(e11 * b1 + e21);
    *reinterpret_cast<unsigned int*>(&ob[(size_t)j * DIMSZ]) =
        (unsigned)f2bf(o0) | ((unsigned)f2bf(o1) << 16);
    // state update (decay w)
    wkv_step(p0, a0, b0, k0, v0, w2.x);
    wkv_step(p1, a1, b1, k1, v1, w2.y);
  }
}

extern "C" void kernel_launch(void* const* d_in, const int* in_sizes, int n_in,
                              void* d_out, int out_size, void* d_ws, size_t ws_size,
                              hipStream_t stream) {
  const float* x  = (const float*)d_in[0];
  // d_in[1]=Wq, d_in[2]=bq: unused by the reference forward
  const float* Wk = (const float*)d_in[3];
  const float* bk = (const float*)d_in[4];
  const float* Wv = (const float*)d_in[5];
  const float* bv = (const float*)d_in[6];
  const float* wr = (const float*)d_in[7];
  const float* ur = (const float*)d_in[8];
  const float* Wo = (const float*)d_in[9];
  const float* bo = (const float*)d_in[10];
  float* out = (float*)d_out;

  char* ws = (char*)d_ws;
  unsigned short* xb   = (unsigned short*)(ws);               // 32MB  [16384][1024] bf16 (reused as O)
  unsigned short* WTkv = (unsigned short*)(ws + 33554432);    // 4MB   [2048][1024] bf16 (Wk^T ; Wv^T)
  unsigned short* WoT  = (unsigned short*)(ws + 37748736);    // 2MB   [1024][1024] bf16
  unsigned short* kvb  = (unsigned short*)(ws + 39845888);    // 64MB  [16384][2048] bf16

  // chunk-state scratch lives in d_out (64MB f32): fully overwritten by the
  // final GEMM afterwards, so this is free scratch during the wkv phase.
  float* stP = out;                       // 2MB (CCH*NCHAN floats)
  float* stA = out + CCH * NCHAN;         // 2MB
  float* stB = out + 2 * CCH * NCHAN;     // 2MB

  cast_x_kernel<<<dim3(16384), dim3(256), 0, stream>>>(x, xb);
  transpose_cast_kernel<<<dim3(32, 32), dim3(256), 0, stream>>>(Wk, WTkv);
  transpose_cast_kernel<<<dim3(32, 32), dim3(256), 0, stream>>>(Wv, WTkv + 1024 * 1024);
  transpose_cast_kernel<<<dim3(32, 32), dim3(256), 0, stream>>>(Wo, WoT);

  // k|v projection: [16384][1024] @ [1024][2048] -> bf16 kv buffer (+bk|bv)
  gemm256_kernel<1><<<dim3(64, 8), dim3(512), 131072, stream>>>(
      xb, WTkv, (void*)kvb, bk, bv, MTOT, 2048, 1024, 1024);

  // WKV chunked scan -> O (bf16) into xb (its x-bf16 contents are consumed)
  wkv_chunk_state_kernel<<<dim3(CCH * NB * 512 / 256), dim3(256), 0, stream>>>(
      kvb, wr, stP, stA, stB);
  wkv_scan_kernel<<<dim3(NCHAN / 256), dim3(256), 0, stream>>>(wr, stP, stA, stB);
  wkv_out_kernel<<<dim3(CCH * NB * 512 / 256), dim3(256), 0, stream>>>(
      kvb, wr, ur, stP, stA, stB, xb);

  // output projection: [16384][1024] @ [1024][1024] -> f32 d_out (+bo)
  gemm256_kernel<0><<<dim3(64, 4), dim3(512), 131072, stream>>>(
      xb, WoT, (void*)out, bo, bo, MTOT, 1024, 1024, 1024);
}